// Round 1
// baseline (1253.068 us; speedup 1.0000x reference)
//
#include <hip/hip_runtime.h>

#define BATCH 8
#define C_DIM 768
#define HW 2304
#define N_TOK 18432   // BATCH*HW
#define E_NUM 8
#define HID 1536

#define TM 64
#define TN 64
#define TKA 16
#define MAXTM (N_TOK / TM)       // 288
#define TILESN_A (HID / TN)      // 24
#define TILESN_B (C_DIM / TN)    // 12

__device__ __forceinline__ float bf2f(unsigned short u) {
  return __uint_as_float(((unsigned int)u) << 16);
}
__device__ __forceinline__ unsigned short f2bf(float f) {
  unsigned int u = __float_as_uint(f);
  u = u + 0x7fffu + ((u >> 16) & 1u);
  return (unsigned short)(u >> 16);
}

// x (B, C, HW) -> xt (N, C)
__global__ __launch_bounds__(256) void k_transpose_in(const float* __restrict__ x,
                                                      float* __restrict__ xt) {
  __shared__ float tile[32][33];
  const int b = blockIdx.z;
  const int c0 = blockIdx.y * 32;
  const int hw0 = blockIdx.x * 32;
  const int tx = threadIdx.x, ty = threadIdx.y;  // 32 x 8
  const float* xb = x + (size_t)b * C_DIM * HW;
#pragma unroll
  for (int i = 0; i < 4; i++) {
    tile[ty + i * 8][tx] = xb[(size_t)(c0 + ty + i * 8) * HW + hw0 + tx];
  }
  __syncthreads();
  float* xtb = xt + (size_t)b * HW * C_DIM;
#pragma unroll
  for (int i = 0; i < 4; i++) {
    xtb[(size_t)(hw0 + ty + i * 8) * C_DIM + c0 + tx] = tile[tx][ty + i * 8];
  }
}

// y (N, C) -> out (B, C, HW)
__global__ __launch_bounds__(256) void k_transpose_out(const float* __restrict__ y,
                                                       float* __restrict__ out) {
  __shared__ float tile[32][33];
  const int b = blockIdx.z;
  const int c0 = blockIdx.y * 32;
  const int hw0 = blockIdx.x * 32;
  const int tx = threadIdx.x, ty = threadIdx.y;
  const float* yb = y + (size_t)b * HW * C_DIM;
#pragma unroll
  for (int i = 0; i < 4; i++) {
    tile[ty + i * 8][tx] = yb[(size_t)(hw0 + ty + i * 8) * C_DIM + c0 + tx];
  }
  __syncthreads();
  float* ob = out + (size_t)b * C_DIM * HW;
#pragma unroll
  for (int i = 0; i < 4; i++) {
    ob[(size_t)(c0 + ty + i * 8) * HW + hw0 + tx] = tile[tx][ty + i * 8];
  }
}

// gating: 1 wave per token
__global__ __launch_bounds__(256) void k_gate(const float* __restrict__ xt,
                                              const float* __restrict__ noise,
                                              const float* __restrict__ wg,
                                              const float* __restrict__ bg,
                                              const float* __restrict__ wn,
                                              const float* __restrict__ bn,
                                              int* __restrict__ counts,
                                              int* __restrict__ tok_list,
                                              float* __restrict__ wt_list) {
  const int wave = threadIdx.x >> 6;
  const int lane = threadIdx.x & 63;
  const int n = blockIdx.x * 4 + wave;
  if (n >= N_TOK) return;
  const float* xr = xt + (size_t)n * C_DIM;
  float accg[E_NUM] = {};
  float accn[E_NUM] = {};
  for (int c = lane; c < C_DIM; c += 64) {
    const float xv = xr[c];
    const float* wgc = wg + c * E_NUM;
    const float* wnc = wn + c * E_NUM;
#pragma unroll
    for (int e = 0; e < E_NUM; e++) {
      accg[e] = fmaf(xv, wgc[e], accg[e]);
      accn[e] = fmaf(xv, wnc[e], accn[e]);
    }
  }
#pragma unroll
  for (int off = 32; off >= 1; off >>= 1) {
#pragma unroll
    for (int e = 0; e < E_NUM; e++) {
      accg[e] += __shfl_xor(accg[e], off, 64);
      accn[e] += __shfl_xor(accn[e], off, 64);
    }
  }
  if (lane == 0) {
    float noisy[E_NUM];
#pragma unroll
    for (int e = 0; e < E_NUM; e++) {
      const float lg = accg[e] + bg[e];
      const float nl = accn[e] + bn[e];
      const float sp = (nl > 20.f) ? nl : log1pf(expf(nl));
      noisy[e] = lg + noise[(size_t)n * E_NUM + e] * sp;
    }
    // top-2, lowest index wins ties (strict >)
    int i0 = 0;
#pragma unroll
    for (int e = 1; e < E_NUM; e++) if (noisy[e] > noisy[i0]) i0 = e;
    int i1 = (i0 == 0) ? 1 : 0;
#pragma unroll
    for (int e = 0; e < E_NUM; e++) if (e != i0 && noisy[e] > noisy[i1]) i1 = e;
    const float v0 = noisy[i0], v1 = noisy[i1];
    const float e1 = expf(v1 - v0);
    const float z = 1.f + e1;
    // probs column 0 / column 1 of softmax(sparse) -- the reference's slot_w
    const float p0 = (i0 == 0) ? (1.f / z) : ((i1 == 0) ? (e1 / z) : 0.f);
    const float p1 = (i0 == 1) ? (1.f / z) : ((i1 == 1) ? (e1 / z) : 0.f);
    if (p0 != 0.f) {
      const int pos = atomicAdd(&counts[i0], 1);
      tok_list[i0 * N_TOK + pos] = n;
      wt_list[i0 * N_TOK + pos] = p0;
    }
    if (p1 != 0.f) {
      const int pos = atomicAdd(&counts[i1], 1);
      tok_list[i1 * N_TOK + pos] = n;
      wt_list[i1 * N_TOK + pos] = p1;
    }
  }
}

__global__ void k_scan(const int* __restrict__ counts, int* __restrict__ offsets) {
  if (threadIdx.x == 0) {
    int s = 0;
    for (int e = 0; e < E_NUM; e++) { offsets[e] = s; s += counts[e]; }
    offsets[E_NUM] = s;
  }
}

// pass A: H[pair, :] = silu(x@w1+b1) * (x@w3+b3), grouped per expert
__global__ __launch_bounds__(256) void k_ffn_a(
    const float* __restrict__ xt, const float* __restrict__ w1,
    const float* __restrict__ b1, const float* __restrict__ w3,
    const float* __restrict__ b3, const int* __restrict__ counts,
    const int* __restrict__ offsets, const int* __restrict__ tok_list,
    unsigned short* __restrict__ H) {
  __shared__ float As[TKA][TM];
  __shared__ float B1s[TKA][TN];
  __shared__ float B3s[TKA][TN];
  const int tid = threadIdx.x;
  const int row = tid >> 2, kq = tid & 3;          // A-tile load
  const int bk = tid >> 4, bc = (tid & 15) << 2;   // B-tile load
  const int ty = tid >> 4, tx = tid & 15;          // compute
  const int total = E_NUM * MAXTM * TILESN_A;
  for (int vt = blockIdx.x; vt < total; vt += gridDim.x) {
    const int e = vt / (MAXTM * TILESN_A);
    const int rem = vt - e * (MAXTM * TILESN_A);
    const int tm = rem / TILESN_A;
    const int cnt = counts[e];
    const int m0 = tm * TM;
    if (m0 >= cnt) continue;
    const int tn = rem - tm * TILESN_A;
    const int n0 = tn * TN;
    const int gm = m0 + row;
    const int tok = (gm < cnt) ? tok_list[e * N_TOK + gm] : -1;
    float acc1[4][4] = {};
    float acc3[4][4] = {};
    const float* w1base = w1 + (size_t)e * C_DIM * HID + n0 + bc;
    const float* w3base = w3 + (size_t)e * C_DIM * HID + n0 + bc;
    for (int k0 = 0; k0 < C_DIM; k0 += TKA) {
      float4 av = make_float4(0.f, 0.f, 0.f, 0.f);
      if (tok >= 0) av = *(const float4*)(xt + (size_t)tok * C_DIM + k0 + (kq << 2));
      const float4 b1v = *(const float4*)(w1base + (size_t)(k0 + bk) * HID);
      const float4 b3v = *(const float4*)(w3base + (size_t)(k0 + bk) * HID);
      __syncthreads();
      As[(kq << 2) + 0][row] = av.x;
      As[(kq << 2) + 1][row] = av.y;
      As[(kq << 2) + 2][row] = av.z;
      As[(kq << 2) + 3][row] = av.w;
      *(float4*)&B1s[bk][bc] = b1v;
      *(float4*)&B3s[bk][bc] = b3v;
      __syncthreads();
#pragma unroll
      for (int kk = 0; kk < TKA; kk++) {
        float a[4], p1[4], p3[4];
#pragma unroll
        for (int i = 0; i < 4; i++) a[i] = As[kk][(ty << 2) + i];
#pragma unroll
        for (int j = 0; j < 4; j++) { p1[j] = B1s[kk][(tx << 2) + j]; p3[j] = B3s[kk][(tx << 2) + j]; }
#pragma unroll
        for (int i = 0; i < 4; i++)
#pragma unroll
          for (int j = 0; j < 4; j++) {
            acc1[i][j] = fmaf(a[i], p1[j], acc1[i][j]);
            acc3[i][j] = fmaf(a[i], p3[j], acc3[i][j]);
          }
      }
    }
    const int hbase = offsets[e] + m0;
#pragma unroll
    for (int i = 0; i < 4; i++) {
      const int m = (ty << 2) + i;
      if (m0 + m < cnt) {
        ushort4 pack;
        unsigned short hv[4];
#pragma unroll
        for (int j = 0; j < 4; j++) {
          const int c = n0 + (tx << 2) + j;
          const float g1 = acc1[i][j] + b1[e * HID + c];
          const float g3 = acc3[i][j] + b3[e * HID + c];
          const float s = g1 / (1.f + expf(-g1));
          hv[j] = f2bf(s * g3);
        }
        pack.x = hv[0]; pack.y = hv[1]; pack.z = hv[2]; pack.w = hv[3];
        *(ushort4*)(H + (size_t)(hbase + m) * HID + n0 + (tx << 2)) = pack;
      }
    }
    __syncthreads();
  }
}

// pass B: y[tok] += (H @ w2 + b2) * weight (atomic, (N,C) layout)
__global__ __launch_bounds__(256) void k_ffn_b(
    const unsigned short* __restrict__ H, const float* __restrict__ w2,
    const float* __restrict__ b2, const int* __restrict__ counts,
    const int* __restrict__ offsets, const int* __restrict__ tok_list,
    const float* __restrict__ wt_list, float* __restrict__ y) {
  __shared__ float As[TKA][TM];
  __shared__ float Bs[TKA][TN];
  const int tid = threadIdx.x;
  const int row = tid >> 2, kq = tid & 3;
  const int bk = tid >> 4, bc = (tid & 15) << 2;
  const int ty = tid >> 4, tx = tid & 15;
  const int total = E_NUM * MAXTM * TILESN_B;
  for (int vt = blockIdx.x; vt < total; vt += gridDim.x) {
    const int e = vt / (MAXTM * TILESN_B);
    const int rem = vt - e * (MAXTM * TILESN_B);
    const int tm = rem / TILESN_B;
    const int cnt = counts[e];
    const int m0 = tm * TM;
    if (m0 >= cnt) continue;
    const int tn = rem - tm * TILESN_B;
    const int n0 = tn * TN;
    const int gm = m0 + row;
    const bool valid = (gm < cnt);
    const size_t hrow = (size_t)(offsets[e] + gm) * HID;
    float acc[4][4] = {};
    const float* w2base = w2 + (size_t)e * HID * C_DIM + n0 + bc;
    for (int k0 = 0; k0 < HID; k0 += TKA) {
      ushort4 hv = make_ushort4(0, 0, 0, 0);
      if (valid) hv = *(const ushort4*)(H + hrow + k0 + (kq << 2));
      const float4 bv = *(const float4*)(w2base + (size_t)(k0 + bk) * C_DIM);
      __syncthreads();
      As[(kq << 2) + 0][row] = bf2f(hv.x);
      As[(kq << 2) + 1][row] = bf2f(hv.y);
      As[(kq << 2) + 2][row] = bf2f(hv.z);
      As[(kq << 2) + 3][row] = bf2f(hv.w);
      *(float4*)&Bs[bk][bc] = bv;
      __syncthreads();
#pragma unroll
      for (int kk = 0; kk < TKA; kk++) {
        float a[4], p[4];
#pragma unroll
        for (int i = 0; i < 4; i++) a[i] = As[kk][(ty << 2) + i];
#pragma unroll
        for (int j = 0; j < 4; j++) p[j] = Bs[kk][(tx << 2) + j];
#pragma unroll
        for (int i = 0; i < 4; i++)
#pragma unroll
          for (int j = 0; j < 4; j++) acc[i][j] = fmaf(a[i], p[j], acc[i][j]);
      }
    }
#pragma unroll
    for (int i = 0; i < 4; i++) {
      const int m = (ty << 2) + i;
      if (m0 + m < cnt) {
        const int t = tok_list[e * N_TOK + m0 + m];
        const float wgt = wt_list[e * N_TOK + m0 + m];
#pragma unroll
        for (int j = 0; j < 4; j++) {
          const int c = n0 + (tx << 2) + j;
          atomicAdd(&y[(size_t)t * C_DIM + c], (acc[i][j] + b2[e * C_DIM + c]) * wgt);
        }
      }
    }
    __syncthreads();
  }
}

extern "C" void kernel_launch(void* const* d_in, const int* in_sizes, int n_in,
                              void* d_out, int out_size, void* d_ws, size_t ws_size,
                              hipStream_t stream) {
  const float* x = (const float*)d_in[0];
  const float* noise = (const float*)d_in[1];
  const float* wg = (const float*)d_in[2];
  const float* bg = (const float*)d_in[3];
  const float* wn = (const float*)d_in[4];
  const float* bn = (const float*)d_in[5];
  const float* w1 = (const float*)d_in[6];
  const float* b1 = (const float*)d_in[7];
  const float* w2 = (const float*)d_in[8];
  const float* b2 = (const float*)d_in[9];
  const float* w3 = (const float*)d_in[10];
  const float* b3 = (const float*)d_in[11];
  float* out = (float*)d_out;

  char* ws = (char*)d_ws;
  float* xt = (float*)ws;            ws += (size_t)N_TOK * C_DIM * 4;
  float* y = (float*)ws;             ws += (size_t)N_TOK * C_DIM * 4;
  int* counts = (int*)ws;            ws += 64;
  int* offsets = (int*)ws;           ws += 64;
  int* tok_list = (int*)ws;          ws += (size_t)E_NUM * N_TOK * 4;
  float* wt_list = (float*)ws;       ws += (size_t)E_NUM * N_TOK * 4;
  unsigned short* H = (unsigned short*)ws;  // capacity 2N x HID bf16

  hipMemsetAsync(y, 0, (size_t)N_TOK * C_DIM * 4, stream);
  hipMemsetAsync(counts, 0, 64, stream);

  k_transpose_in<<<dim3(HW / 32, C_DIM / 32, BATCH), dim3(32, 8), 0, stream>>>(x, xt);
  k_gate<<<dim3(N_TOK / 4), dim3(256), 0, stream>>>(xt, noise, wg, bg, wn, bn,
                                                    counts, tok_list, wt_list);
  k_scan<<<1, 32, 0, stream>>>(counts, offsets);
  k_ffn_a<<<dim3(2048), dim3(256), 0, stream>>>(xt, w1, b1, w3, b3, counts, offsets,
                                                tok_list, H);
  k_ffn_b<<<dim3(2048), dim3(256), 0, stream>>>(H, w2, b2, counts, offsets, tok_list,
                                                wt_list, y);
  k_transpose_out<<<dim3(HW / 32, C_DIM / 32, BATCH), dim3(32, 8), 0, stream>>>(y, out);
}

// Round 2
// 494.335 us; speedup vs baseline: 2.5349x; 2.5349x over previous
//
#include <hip/hip_runtime.h>

#define BATCH 8
#define C_DIM 768
#define HW 2304
#define N_TOK 18432   // BATCH*HW
#define E_NUM 8
#define HID 1536

#define BM 128
#define MT (N_TOK / BM)          // 144 max M-tiles per expert
#define NT_A (HID / 64)          // 24 (BN=64 per matrix, two matrices)
#define NT_B (C_DIM / 128)       // 6  (BN=128)
#define LDA 40                   // 32 + 8 pad (shorts) -> 80B row stride

typedef short s16x8 __attribute__((ext_vector_type(8)));
typedef float f32x4 __attribute__((ext_vector_type(4)));

__device__ __forceinline__ unsigned short f2bf(float f) {
  unsigned int u = __float_as_uint(f);
  u = u + 0x7fffu + ((u >> 16) & 1u);
  return (unsigned short)(u >> 16);
}

// x (B, C, HW) -> xt (N, C) fp32  +  Xbf (N, C) bf16
__global__ __launch_bounds__(256) void k_transpose_in(const float* __restrict__ x,
                                                      float* __restrict__ xt,
                                                      unsigned short* __restrict__ Xbf) {
  __shared__ float tile[32][33];
  const int b = blockIdx.z;
  const int c0 = blockIdx.y * 32;
  const int hw0 = blockIdx.x * 32;
  const int tx = threadIdx.x, ty = threadIdx.y;  // 32 x 8
  const float* xb = x + (size_t)b * C_DIM * HW;
#pragma unroll
  for (int i = 0; i < 4; i++) {
    tile[ty + i * 8][tx] = xb[(size_t)(c0 + ty + i * 8) * HW + hw0 + tx];
  }
  __syncthreads();
#pragma unroll
  for (int i = 0; i < 4; i++) {
    const size_t idx = (size_t)b * HW * C_DIM + (size_t)(hw0 + ty + i * 8) * C_DIM + c0 + tx;
    const float v = tile[tx][ty + i * 8];
    xt[idx] = v;
    Xbf[idx] = f2bf(v);
  }
}

// per-expert matrix transpose + bf16 convert: in (R,S) fp32 -> out (S,R) bf16
__global__ __launch_bounds__(256) void k_prep_w(const float* __restrict__ in,
                                                unsigned short* __restrict__ outT,
                                                int R, int S) {
  __shared__ float tile[32][33];
  const int e = blockIdx.z;
  const int s0 = blockIdx.x * 32, r0 = blockIdx.y * 32;
  const int tx = threadIdx.x, ty = threadIdx.y;
  const float* ip = in + (size_t)e * R * S;
  unsigned short* op = outT + (size_t)e * R * S;
#pragma unroll
  for (int i = 0; i < 4; i++) {
    tile[ty + i * 8][tx] = ip[(size_t)(r0 + ty + i * 8) * S + s0 + tx];
  }
  __syncthreads();
#pragma unroll
  for (int i = 0; i < 4; i++) {
    op[(size_t)(s0 + ty + i * 8) * R + r0 + tx] = f2bf(tile[tx][ty + i * 8]);
  }
}

// gating: 1 wave per token, exact fp32
__global__ __launch_bounds__(256) void k_gate(const float* __restrict__ xt,
                                              const float* __restrict__ noise,
                                              const float* __restrict__ wg,
                                              const float* __restrict__ bg,
                                              const float* __restrict__ wn,
                                              const float* __restrict__ bn,
                                              int* __restrict__ counts,
                                              int* __restrict__ tok_list,
                                              int* __restrict__ pairE,
                                              int* __restrict__ pairPos,
                                              float* __restrict__ pairW) {
  const int wave = threadIdx.x >> 6;
  const int lane = threadIdx.x & 63;
  const int n = blockIdx.x * 4 + wave;
  if (n >= N_TOK) return;
  const float* xr = xt + (size_t)n * C_DIM;
  float accg[E_NUM] = {};
  float accn[E_NUM] = {};
  for (int c = lane; c < C_DIM; c += 64) {
    const float xv = xr[c];
    const float* wgc = wg + c * E_NUM;
    const float* wnc = wn + c * E_NUM;
#pragma unroll
    for (int e = 0; e < E_NUM; e++) {
      accg[e] = fmaf(xv, wgc[e], accg[e]);
      accn[e] = fmaf(xv, wnc[e], accn[e]);
    }
  }
#pragma unroll
  for (int off = 32; off >= 1; off >>= 1) {
#pragma unroll
    for (int e = 0; e < E_NUM; e++) {
      accg[e] += __shfl_xor(accg[e], off, 64);
      accn[e] += __shfl_xor(accn[e], off, 64);
    }
  }
  if (lane == 0) {
    float noisy[E_NUM];
#pragma unroll
    for (int e = 0; e < E_NUM; e++) {
      const float lg = accg[e] + bg[e];
      const float nl = accn[e] + bn[e];
      const float sp = (nl > 20.f) ? nl : log1pf(expf(nl));
      noisy[e] = lg + noise[(size_t)n * E_NUM + e] * sp;
    }
    int i0 = 0;
#pragma unroll
    for (int e = 1; e < E_NUM; e++) if (noisy[e] > noisy[i0]) i0 = e;
    int i1 = (i0 == 0) ? 1 : 0;
#pragma unroll
    for (int e = 0; e < E_NUM; e++) if (e != i0 && noisy[e] > noisy[i1]) i1 = e;
    const float v0 = noisy[i0], v1 = noisy[i1];
    const float e1 = expf(v1 - v0);
    const float z = 1.f + e1;
    const float p0 = (i0 == 0) ? (1.f / z) : ((i1 == 0) ? (e1 / z) : 0.f);
    const float p1 = (i0 == 1) ? (1.f / z) : ((i1 == 1) ? (e1 / z) : 0.f);
    if (p0 != 0.f) {
      const int pos = atomicAdd(&counts[i0], 1);
      tok_list[i0 * N_TOK + pos] = n;
      pairE[2 * n] = i0; pairPos[2 * n] = pos; pairW[2 * n] = p0;
    } else {
      pairE[2 * n] = -1;
    }
    if (p1 != 0.f) {
      const int pos = atomicAdd(&counts[i1], 1);
      tok_list[i1 * N_TOK + pos] = n;
      pairE[2 * n + 1] = i1; pairPos[2 * n + 1] = pos; pairW[2 * n + 1] = p1;
    } else {
      pairE[2 * n + 1] = -1;
    }
  }
}

__global__ void k_scan(int* __restrict__ counts, int* __restrict__ offsets) {
  if (threadIdx.x == 0) {
    int s = 0;
    for (int e = 0; e < E_NUM; e++) {
      offsets[e] = s;
      int c = counts[e];
      if (s + c > N_TOK) c = N_TOK - s;  // impossible statistically; OOB guard
      counts[e] = c;
      s += c;
    }
    offsets[E_NUM] = s;
  }
}

// pass A: H = silu(Xg@w1+b1) * (Xg@w3+b3), MFMA bf16, BM=128 x BN=64 (x2 mats)
__global__ __launch_bounds__(256) void k_ffn_a(
    const unsigned short* __restrict__ Xbf, const unsigned short* __restrict__ w1t,
    const float* __restrict__ b1, const unsigned short* __restrict__ w3t,
    const float* __restrict__ b3, const int* __restrict__ counts,
    const int* __restrict__ offsets, const int* __restrict__ tok_list,
    unsigned short* __restrict__ H) {
  __shared__ __align__(16) unsigned short As[BM * LDA];
  __shared__ __align__(16) unsigned short B1s[64 * LDA];
  __shared__ __align__(16) unsigned short B3s[64 * LDA];
  const int tid = threadIdx.x;
  const int lane = tid & 63;
  const int w = tid >> 6;
  const int wm = w >> 1, wn = w & 1;
  const int lrow = lane & 15, lgrp = lane >> 4;
  const int arow = tid & 127, akh = tid >> 7;  // A staging: 2 x 16B at k=akh*16+{0,8}
  const int brow = tid & 63, bkh = tid >> 6;   // B staging: 1 x 16B at k=bkh*8
  const int total = E_NUM * MT * NT_A;
  for (int vt = blockIdx.x; vt < total; vt += gridDim.x) {
    const int e = vt / (MT * NT_A);
    const int rem = vt - e * (MT * NT_A);
    const int tm = rem / NT_A;
    const int cnt = counts[e];
    const int m0 = tm * BM;
    if (m0 >= cnt) continue;
    const int tn = rem - tm * NT_A;
    const int n0 = tn * 64;
    const int gm = m0 + arow;
    const int tok = (gm < cnt) ? tok_list[e * N_TOK + gm] : -1;
    const unsigned short* aptr = (tok >= 0) ? (Xbf + (size_t)tok * C_DIM + akh * 16) : nullptr;
    const unsigned short* b1p = w1t + ((size_t)e * HID + n0 + brow) * C_DIM + bkh * 8;
    const unsigned short* b3p = w3t + ((size_t)e * HID + n0 + brow) * C_DIM + bkh * 8;
    f32x4 acc1[4][2] = {};
    f32x4 acc3[4][2] = {};
    for (int k0 = 0; k0 < C_DIM; k0 += 32) {
      uint4 a0 = make_uint4(0, 0, 0, 0), a1 = make_uint4(0, 0, 0, 0);
      if (aptr) {
        a0 = *(const uint4*)(aptr + k0);
        a1 = *(const uint4*)(aptr + k0 + 8);
      }
      const uint4 bv1 = *(const uint4*)(b1p + k0);
      const uint4 bv3 = *(const uint4*)(b3p + k0);
      __syncthreads();
      *(uint4*)&As[arow * LDA + akh * 16] = a0;
      *(uint4*)&As[arow * LDA + akh * 16 + 8] = a1;
      *(uint4*)&B1s[brow * LDA + bkh * 8] = bv1;
      *(uint4*)&B3s[brow * LDA + bkh * 8] = bv3;
      __syncthreads();
      s16x8 af[4], bf1[2], bf3[2];
#pragma unroll
      for (int mf = 0; mf < 4; mf++)
        af[mf] = *(const s16x8*)&As[(wm * 64 + mf * 16 + lrow) * LDA + lgrp * 8];
#pragma unroll
      for (int nf = 0; nf < 2; nf++) {
        bf1[nf] = *(const s16x8*)&B1s[(wn * 32 + nf * 16 + lrow) * LDA + lgrp * 8];
        bf3[nf] = *(const s16x8*)&B3s[(wn * 32 + nf * 16 + lrow) * LDA + lgrp * 8];
      }
#pragma unroll
      for (int mf = 0; mf < 4; mf++)
#pragma unroll
        for (int nf = 0; nf < 2; nf++) {
          acc1[mf][nf] = __builtin_amdgcn_mfma_f32_16x16x32_bf16(af[mf], bf1[nf], acc1[mf][nf], 0, 0, 0);
          acc3[mf][nf] = __builtin_amdgcn_mfma_f32_16x16x32_bf16(af[mf], bf3[nf], acc3[mf][nf], 0, 0, 0);
        }
    }
    const int hb = offsets[e] + m0;
#pragma unroll
    for (int mf = 0; mf < 4; mf++)
#pragma unroll
      for (int nf = 0; nf < 2; nf++) {
        const int col = n0 + wn * 32 + nf * 16 + lrow;
        const float bb1 = b1[e * HID + col];
        const float bb3 = b3[e * HID + col];
#pragma unroll
        for (int r = 0; r < 4; r++) {
          const int gr = wm * 64 + mf * 16 + lgrp * 4 + r;
          if (m0 + gr < cnt) {
            const float g1 = acc1[mf][nf][r] + bb1;
            const float g3 = acc3[mf][nf][r] + bb3;
            const float hv = g1 / (1.f + expf(-g1)) * g3;
            H[(size_t)(hb + gr) * HID + col] = f2bf(hv);
          }
        }
      }
  }
}

// pass B: Out = H @ w2 + b2 (no weight), MFMA bf16, BM=128 x BN=128
__global__ __launch_bounds__(256) void k_ffn_b(
    const unsigned short* __restrict__ H, const unsigned short* __restrict__ w2t,
    const float* __restrict__ b2, const int* __restrict__ counts,
    const int* __restrict__ offsets, float* __restrict__ Out) {
  __shared__ __align__(16) unsigned short As[BM * LDA];
  __shared__ __align__(16) unsigned short Bs[128 * LDA];
  const int tid = threadIdx.x;
  const int lane = tid & 63;
  const int w = tid >> 6;
  const int wm = w >> 1, wn = w & 1;
  const int lrow = lane & 15, lgrp = lane >> 4;
  const int arow = tid & 127, akh = tid >> 7;
  const int total = E_NUM * MT * NT_B;
  for (int vt = blockIdx.x; vt < total; vt += gridDim.x) {
    const int e = vt / (MT * NT_B);
    const int rem = vt - e * (MT * NT_B);
    const int tm = rem / NT_B;
    const int cnt = counts[e];
    const int m0 = tm * BM;
    if (m0 >= cnt) continue;
    const int tn = rem - tm * NT_B;
    const int n0 = tn * 128;
    const int hb = offsets[e] + m0;
    const bool avalid = (m0 + arow < cnt);
    const unsigned short* aptr = H + (size_t)(hb + arow) * HID + akh * 16;
    const unsigned short* bp = w2t + ((size_t)e * C_DIM + n0 + arow) * HID + akh * 16;
    f32x4 acc[4][4] = {};
    for (int k0 = 0; k0 < HID; k0 += 32) {
      uint4 a0 = make_uint4(0, 0, 0, 0), a1 = make_uint4(0, 0, 0, 0);
      if (avalid) {
        a0 = *(const uint4*)(aptr + k0);
        a1 = *(const uint4*)(aptr + k0 + 8);
      }
      const uint4 b0 = *(const uint4*)(bp + k0);
      const uint4 b1v = *(const uint4*)(bp + k0 + 8);
      __syncthreads();
      *(uint4*)&As[arow * LDA + akh * 16] = a0;
      *(uint4*)&As[arow * LDA + akh * 16 + 8] = a1;
      *(uint4*)&Bs[arow * LDA + akh * 16] = b0;
      *(uint4*)&Bs[arow * LDA + akh * 16 + 8] = b1v;
      __syncthreads();
      s16x8 af[4], bfr[4];
#pragma unroll
      for (int mf = 0; mf < 4; mf++)
        af[mf] = *(const s16x8*)&As[(wm * 64 + mf * 16 + lrow) * LDA + lgrp * 8];
#pragma unroll
      for (int nf = 0; nf < 4; nf++)
        bfr[nf] = *(const s16x8*)&Bs[(wn * 64 + nf * 16 + lrow) * LDA + lgrp * 8];
#pragma unroll
      for (int mf = 0; mf < 4; mf++)
#pragma unroll
        for (int nf = 0; nf < 4; nf++)
          acc[mf][nf] = __builtin_amdgcn_mfma_f32_16x16x32_bf16(af[mf], bfr[nf], acc[mf][nf], 0, 0, 0);
    }
#pragma unroll
    for (int mf = 0; mf < 4; mf++)
#pragma unroll
      for (int nf = 0; nf < 4; nf++) {
        const int col = n0 + wn * 64 + nf * 16 + lrow;
        const float bb = b2[e * C_DIM + col];
#pragma unroll
        for (int r = 0; r < 4; r++) {
          const int gr = wm * 64 + mf * 16 + lgrp * 4 + r;
          if (m0 + gr < cnt) {
            Out[(size_t)(hb + gr) * C_DIM + col] = acc[mf][nf][r] + bb;
          }
        }
      }
  }
}

// combine pairs + transpose to (B, C, HW)
__global__ __launch_bounds__(256) void k_combine(
    const float* __restrict__ Out, const int* __restrict__ offsets,
    const int* __restrict__ counts, const int* __restrict__ pairE,
    const int* __restrict__ pairPos, const float* __restrict__ pairW,
    float* __restrict__ out) {
  __shared__ float tile[32][33];
  const int b = blockIdx.z;
  const int c0 = blockIdx.y * 32;
  const int hw0 = blockIdx.x * 32;
  const int tx = threadIdx.x, ty = threadIdx.y;
#pragma unroll
  for (int i = 0; i < 4; i++) {
    const int n = b * HW + hw0 + ty + i * 8;
    float v = 0.f;
#pragma unroll
    for (int s = 0; s < 2; s++) {
      const int e = pairE[2 * n + s];
      if (e >= 0) {
        const int pos = pairPos[2 * n + s];
        if (pos < counts[e]) {
          const int idx = offsets[e] + pos;
          v += pairW[2 * n + s] * Out[(size_t)idx * C_DIM + c0 + tx];
        }
      }
    }
    tile[ty + i * 8][tx] = v;
  }
  __syncthreads();
#pragma unroll
  for (int i = 0; i < 4; i++) {
    out[((size_t)b * C_DIM + c0 + ty + i * 8) * HW + hw0 + tx] = tile[tx][ty + i * 8];
  }
}

extern "C" void kernel_launch(void* const* d_in, const int* in_sizes, int n_in,
                              void* d_out, int out_size, void* d_ws, size_t ws_size,
                              hipStream_t stream) {
  const float* x = (const float*)d_in[0];
  const float* noise = (const float*)d_in[1];
  const float* wg = (const float*)d_in[2];
  const float* bg = (const float*)d_in[3];
  const float* wn = (const float*)d_in[4];
  const float* bn = (const float*)d_in[5];
  const float* w1 = (const float*)d_in[6];
  const float* b1 = (const float*)d_in[7];
  const float* w2 = (const float*)d_in[8];
  const float* b2 = (const float*)d_in[9];
  const float* w3 = (const float*)d_in[10];
  const float* b3 = (const float*)d_in[11];
  float* out = (float*)d_out;

  char* ws = (char*)d_ws;
  float* xt = (float*)ws;                    ws += (size_t)N_TOK * C_DIM * 4;  // aliased as Out later
  float* Outb = xt;
  unsigned short* Xbf = (unsigned short*)ws; ws += (size_t)N_TOK * C_DIM * 2;
  unsigned short* w1t = (unsigned short*)ws; ws += (size_t)E_NUM * C_DIM * HID * 2;
  unsigned short* w3t = (unsigned short*)ws; ws += (size_t)E_NUM * C_DIM * HID * 2;
  unsigned short* w2t = (unsigned short*)ws; ws += (size_t)E_NUM * HID * C_DIM * 2;
  unsigned short* H = (unsigned short*)ws;   ws += (size_t)N_TOK * HID * 2;
  int* counts = (int*)ws;                    ws += 256;
  int* offsets = (int*)ws;                   ws += 256;
  int* tok_list = (int*)ws;                  ws += (size_t)E_NUM * N_TOK * 4;
  int* pairE = (int*)ws;                     ws += (size_t)N_TOK * 2 * 4;
  int* pairPos = (int*)ws;                   ws += (size_t)N_TOK * 2 * 4;
  float* pairW = (float*)ws;                 ws += (size_t)N_TOK * 2 * 4;

  hipMemsetAsync(counts, 0, 64, stream);

  k_transpose_in<<<dim3(HW / 32, C_DIM / 32, BATCH), dim3(32, 8), 0, stream>>>(x, xt, Xbf);
  k_prep_w<<<dim3(HID / 32, C_DIM / 32, E_NUM), dim3(32, 8), 0, stream>>>(w1, w1t, C_DIM, HID);
  k_prep_w<<<dim3(HID / 32, C_DIM / 32, E_NUM), dim3(32, 8), 0, stream>>>(w3, w3t, C_DIM, HID);
  k_prep_w<<<dim3(C_DIM / 32, HID / 32, E_NUM), dim3(32, 8), 0, stream>>>(w2, w2t, HID, C_DIM);
  k_gate<<<dim3(N_TOK / 4), dim3(256), 0, stream>>>(xt, noise, wg, bg, wn, bn,
                                                    counts, tok_list, pairE, pairPos, pairW);
  k_scan<<<1, 32, 0, stream>>>(counts, offsets);
  k_ffn_a<<<dim3(2048), dim3(256), 0, stream>>>(Xbf, w1t, b1, w3t, b3, counts, offsets,
                                                tok_list, H);
  k_ffn_b<<<dim3(2048), dim3(256), 0, stream>>>(H, w2t, b2, counts, offsets, Outb);
  k_combine<<<dim3(HW / 32, C_DIM / 32, BATCH), dim3(32, 8), 0, stream>>>(
      Outb, offsets, counts, pairE, pairPos, pairW, out);
}

// Round 3
// 435.284 us; speedup vs baseline: 2.8787x; 1.1357x over previous
//
#include <hip/hip_runtime.h>

#define BATCH 8
#define C_DIM 768
#define HW 2304
#define N_TOK 18432   // BATCH*HW
#define E_NUM 8
#define HID 1536

#define BM 128
#define MT (N_TOK / BM)          // 144 max M-tiles per expert
#define NT_A (HID / 64)          // 24 (BN=64, two B matrices)
#define NT_B (C_DIM / 64)        // 12 (BN=64)
#define NKA (C_DIM / 32)         // 24 K-steps pass A
#define NKB (HID / 32)           // 48 K-steps pass B

typedef short s16x8 __attribute__((ext_vector_type(8)));
typedef float f32x4 __attribute__((ext_vector_type(4)));

__device__ __forceinline__ unsigned short f2bf(float f) {
  unsigned int u = __float_as_uint(f);
  u = u + 0x7fffu + ((u >> 16) & 1u);
  return (unsigned short)(u >> 16);
}

// async global -> LDS, 16B per lane; LDS dest = wave-uniform base + lane*16
__device__ __forceinline__ void gll16(const unsigned short* g, unsigned short* l) {
  __builtin_amdgcn_global_load_lds(
      (const __attribute__((address_space(1))) unsigned int*)g,
      (__attribute__((address_space(3))) unsigned int*)l, 16, 0, 0);
}

// x (B, C, HW) -> xt (N, C) fp32  +  Xbf (N, C) bf16
__global__ __launch_bounds__(256) void k_transpose_in(const float* __restrict__ x,
                                                      float* __restrict__ xt,
                                                      unsigned short* __restrict__ Xbf) {
  __shared__ float tile[32][33];
  const int b = blockIdx.z;
  const int c0 = blockIdx.y * 32;
  const int hw0 = blockIdx.x * 32;
  const int tx = threadIdx.x, ty = threadIdx.y;  // 32 x 8
  const float* xb = x + (size_t)b * C_DIM * HW;
#pragma unroll
  for (int i = 0; i < 4; i++) {
    tile[ty + i * 8][tx] = xb[(size_t)(c0 + ty + i * 8) * HW + hw0 + tx];
  }
  __syncthreads();
#pragma unroll
  for (int i = 0; i < 4; i++) {
    const size_t idx = (size_t)b * HW * C_DIM + (size_t)(hw0 + ty + i * 8) * C_DIM + c0 + tx;
    const float v = tile[tx][ty + i * 8];
    xt[idx] = v;
    Xbf[idx] = f2bf(v);
  }
}

// per-expert matrix transpose + bf16 convert: in (R,S) fp32 -> out (S,R) bf16
__global__ __launch_bounds__(256) void k_prep_w(const float* __restrict__ in,
                                                unsigned short* __restrict__ outT,
                                                int R, int S) {
  __shared__ float tile[32][33];
  const int e = blockIdx.z;
  const int s0 = blockIdx.x * 32, r0 = blockIdx.y * 32;
  const int tx = threadIdx.x, ty = threadIdx.y;
  const float* ip = in + (size_t)e * R * S;
  unsigned short* op = outT + (size_t)e * R * S;
#pragma unroll
  for (int i = 0; i < 4; i++) {
    tile[ty + i * 8][tx] = ip[(size_t)(r0 + ty + i * 8) * S + s0 + tx];
  }
  __syncthreads();
#pragma unroll
  for (int i = 0; i < 4; i++) {
    op[(size_t)(s0 + ty + i * 8) * R + r0 + tx] = f2bf(tile[tx][ty + i * 8]);
  }
}

// gating: 1 wave per token, exact fp32
__global__ __launch_bounds__(256) void k_gate(const float* __restrict__ xt,
                                              const float* __restrict__ noise,
                                              const float* __restrict__ wg,
                                              const float* __restrict__ bg,
                                              const float* __restrict__ wn,
                                              const float* __restrict__ bn,
                                              int* __restrict__ counts,
                                              int* __restrict__ tok_list,
                                              int* __restrict__ pairE,
                                              int* __restrict__ pairPos,
                                              float* __restrict__ pairW) {
  const int wave = threadIdx.x >> 6;
  const int lane = threadIdx.x & 63;
  const int n = blockIdx.x * 4 + wave;
  if (n >= N_TOK) return;
  const float* xr = xt + (size_t)n * C_DIM;
  float accg[E_NUM] = {};
  float accn[E_NUM] = {};
  for (int c = lane; c < C_DIM; c += 64) {
    const float xv = xr[c];
    const float* wgc = wg + c * E_NUM;
    const float* wnc = wn + c * E_NUM;
#pragma unroll
    for (int e = 0; e < E_NUM; e++) {
      accg[e] = fmaf(xv, wgc[e], accg[e]);
      accn[e] = fmaf(xv, wnc[e], accn[e]);
    }
  }
#pragma unroll
  for (int off = 32; off >= 1; off >>= 1) {
#pragma unroll
    for (int e = 0; e < E_NUM; e++) {
      accg[e] += __shfl_xor(accg[e], off, 64);
      accn[e] += __shfl_xor(accn[e], off, 64);
    }
  }
  if (lane == 0) {
    float noisy[E_NUM];
#pragma unroll
    for (int e = 0; e < E_NUM; e++) {
      const float lg = accg[e] + bg[e];
      const float nl = accn[e] + bn[e];
      const float sp = (nl > 20.f) ? nl : log1pf(expf(nl));
      noisy[e] = lg + noise[(size_t)n * E_NUM + e] * sp;
    }
    int i0 = 0;
#pragma unroll
    for (int e = 1; e < E_NUM; e++) if (noisy[e] > noisy[i0]) i0 = e;
    int i1 = (i0 == 0) ? 1 : 0;
#pragma unroll
    for (int e = 0; e < E_NUM; e++) if (e != i0 && noisy[e] > noisy[i1]) i1 = e;
    const float v0 = noisy[i0], v1 = noisy[i1];
    const float e1 = expf(v1 - v0);
    const float z = 1.f + e1;
    const float p0 = (i0 == 0) ? (1.f / z) : ((i1 == 0) ? (e1 / z) : 0.f);
    const float p1 = (i0 == 1) ? (1.f / z) : ((i1 == 1) ? (e1 / z) : 0.f);
    if (p0 != 0.f) {
      const int pos = atomicAdd(&counts[i0], 1);
      tok_list[i0 * N_TOK + pos] = n;
      pairE[2 * n] = i0; pairPos[2 * n] = pos; pairW[2 * n] = p0;
    } else {
      pairE[2 * n] = -1;
    }
    if (p1 != 0.f) {
      const int pos = atomicAdd(&counts[i1], 1);
      tok_list[i1 * N_TOK + pos] = n;
      pairE[2 * n + 1] = i1; pairPos[2 * n + 1] = pos; pairW[2 * n + 1] = p1;
    } else {
      pairE[2 * n + 1] = -1;
    }
  }
}

__global__ void k_scan(int* __restrict__ counts, int* __restrict__ offsets) {
  if (threadIdx.x == 0) {
    int s = 0;
    for (int e = 0; e < E_NUM; e++) {
      offsets[e] = s;
      int c = counts[e];
      if (s + c > N_TOK) c = N_TOK - s;  // impossible statistically; OOB guard
      counts[e] = c;
      s += c;
    }
    offsets[E_NUM] = s;
  }
}

// pass A: H = silu(Xg@w1+b1) * (Xg@w3+b3)
// BM=128 x BN=64 (x2 mats), BK=32, global_load_lds + 2-phase prefetch,
// XOR chunk-swizzle (source side + read side; LDS stays linear [r][32]).
__global__ __launch_bounds__(256) void k_ffn_a(
    const unsigned short* __restrict__ Xbf, const unsigned short* __restrict__ w1t,
    const float* __restrict__ b1, const unsigned short* __restrict__ w3t,
    const float* __restrict__ b3, const int* __restrict__ counts,
    const int* __restrict__ offsets, const int* __restrict__ tok_list,
    unsigned short* __restrict__ H) {
  __shared__ __align__(16) unsigned short As[2][BM * 32];
  __shared__ __align__(16) unsigned short B1s[2][64 * 32];
  __shared__ __align__(16) unsigned short B3s[2][64 * 32];
  const int tid = threadIdx.x;
  const int lane = tid & 63;
  const int w = tid >> 6;
  const int wm = w >> 1, wn = w & 1;
  const int lrow = lane & 15, lgrp = lane >> 4;
  const int fswz = (lgrp ^ ((lrow >> 1) & 3)) << 3;   // read-side XOR (ushorts)
  const int r2 = tid >> 2;                            // staging row 0..63
  const int swz = ((tid & 3) ^ ((r2 >> 1) & 3)) << 3; // source-side XOR (ushorts)
  const int wbase = w << 9;                           // wave * 512 ushorts
  const int total = E_NUM * MT * NT_A;
  for (int vt = blockIdx.x; vt < total; vt += gridDim.x) {
    const int e = vt / (MT * NT_A);
    const int rem = vt - e * (MT * NT_A);
    const int tm = rem / NT_A;
    const int cnt = counts[e];
    const int m0 = tm * BM;
    if (m0 >= cnt) continue;
    const int tn = rem - tm * NT_A;
    const int n0 = tn * 64;
    int ga0 = m0 + r2;      if (ga0 > cnt - 1) ga0 = cnt - 1;
    int ga1 = m0 + 64 + r2; if (ga1 > cnt - 1) ga1 = cnt - 1;
    const unsigned short* aS0 = Xbf + (size_t)tok_list[e * N_TOK + ga0] * C_DIM + swz;
    const unsigned short* aS1 = Xbf + (size_t)tok_list[e * N_TOK + ga1] * C_DIM + swz;
    const unsigned short* b1S = w1t + ((size_t)e * HID + n0 + r2) * C_DIM + swz;
    const unsigned short* b3S = w3t + ((size_t)e * HID + n0 + r2) * C_DIM + swz;
    f32x4 acc1[4][2] = {};
    f32x4 acc3[4][2] = {};
    // prologue: stage K-step 0 into buf 0
    gll16(aS0, &As[0][wbase]);
    gll16(aS1, &As[0][2048 + wbase]);
    gll16(b1S, &B1s[0][wbase]);
    gll16(b3S, &B3s[0][wbase]);
    asm volatile("s_waitcnt vmcnt(0)" ::: "memory");
    __syncthreads();
    int buf = 0;
    for (int t = 0; t < NKA; ++t) {
      const int k1 = (t + 1) * 32;
      if (k1 < C_DIM) {  // stage next K-step into buf^1
        gll16(aS0 + k1, &As[buf ^ 1][wbase]);
        gll16(aS1 + k1, &As[buf ^ 1][2048 + wbase]);
        gll16(b1S + k1, &B1s[buf ^ 1][wbase]);
        gll16(b3S + k1, &B3s[buf ^ 1][wbase]);
      }
      s16x8 af[4], bf1[2], bf3[2];
#pragma unroll
      for (int mf = 0; mf < 4; mf++)
        af[mf] = *(const s16x8*)&As[buf][(wm * 64 + mf * 16 + lrow) * 32 + fswz];
#pragma unroll
      for (int nf = 0; nf < 2; nf++) {
        bf1[nf] = *(const s16x8*)&B1s[buf][(wn * 32 + nf * 16 + lrow) * 32 + fswz];
        bf3[nf] = *(const s16x8*)&B3s[buf][(wn * 32 + nf * 16 + lrow) * 32 + fswz];
      }
#pragma unroll
      for (int mf = 0; mf < 4; mf++)
#pragma unroll
        for (int nf = 0; nf < 2; nf++) {
          acc1[mf][nf] = __builtin_amdgcn_mfma_f32_16x16x32_bf16(af[mf], bf1[nf], acc1[mf][nf], 0, 0, 0);
          acc3[mf][nf] = __builtin_amdgcn_mfma_f32_16x16x32_bf16(af[mf], bf3[nf], acc3[mf][nf], 0, 0, 0);
        }
      asm volatile("s_waitcnt vmcnt(0)" ::: "memory");
      __syncthreads();
      buf ^= 1;
    }
    const int hb = offsets[e] + m0;
#pragma unroll
    for (int mf = 0; mf < 4; mf++)
#pragma unroll
      for (int nf = 0; nf < 2; nf++) {
        const int col = n0 + wn * 32 + nf * 16 + lrow;
        const float bb1 = b1[e * HID + col];
        const float bb3 = b3[e * HID + col];
#pragma unroll
        for (int r = 0; r < 4; r++) {
          const int gr = wm * 64 + mf * 16 + lgrp * 4 + r;
          if (m0 + gr < cnt) {
            const float g1 = acc1[mf][nf][r] + bb1;
            const float g3 = acc3[mf][nf][r] + bb3;
            const float hv = g1 / (1.f + expf(-g1)) * g3;
            H[(size_t)(hb + gr) * HID + col] = f2bf(hv);
          }
        }
      }
  }
}

// pass B: Out = H @ w2 + b2, BM=128 x BN=64, BK=32, same pipeline
__global__ __launch_bounds__(256) void k_ffn_b(
    const unsigned short* __restrict__ H, const unsigned short* __restrict__ w2t,
    const float* __restrict__ b2, const int* __restrict__ counts,
    const int* __restrict__ offsets, float* __restrict__ Out) {
  __shared__ __align__(16) unsigned short As[2][BM * 32];
  __shared__ __align__(16) unsigned short Bs[2][64 * 32];
  const int tid = threadIdx.x;
  const int lane = tid & 63;
  const int w = tid >> 6;
  const int wm = w >> 1, wn = w & 1;
  const int lrow = lane & 15, lgrp = lane >> 4;
  const int fswz = (lgrp ^ ((lrow >> 1) & 3)) << 3;
  const int r2 = tid >> 2;
  const int swz = ((tid & 3) ^ ((r2 >> 1) & 3)) << 3;
  const int wbase = w << 9;
  const int total = E_NUM * MT * NT_B;
  for (int vt = blockIdx.x; vt < total; vt += gridDim.x) {
    const int e = vt / (MT * NT_B);
    const int rem = vt - e * (MT * NT_B);
    const int tm = rem / NT_B;
    const int cnt = counts[e];
    const int m0 = tm * BM;
    if (m0 >= cnt) continue;
    const int tn = rem - tm * NT_B;
    const int n0 = tn * 64;
    const int hb = offsets[e] + m0;
    int ga0 = m0 + r2;      if (ga0 > cnt - 1) ga0 = cnt - 1;
    int ga1 = m0 + 64 + r2; if (ga1 > cnt - 1) ga1 = cnt - 1;
    const unsigned short* aS0 = H + (size_t)(offsets[e] + ga0) * HID + swz;
    const unsigned short* aS1 = H + (size_t)(offsets[e] + ga1) * HID + swz;
    const unsigned short* bS = w2t + ((size_t)e * C_DIM + n0 + r2) * HID + swz;
    f32x4 acc[4][2] = {};
    gll16(aS0, &As[0][wbase]);
    gll16(aS1, &As[0][2048 + wbase]);
    gll16(bS, &Bs[0][wbase]);
    asm volatile("s_waitcnt vmcnt(0)" ::: "memory");
    __syncthreads();
    int buf = 0;
    for (int t = 0; t < NKB; ++t) {
      const int k1 = (t + 1) * 32;
      if (k1 < HID) {
        gll16(aS0 + k1, &As[buf ^ 1][wbase]);
        gll16(aS1 + k1, &As[buf ^ 1][2048 + wbase]);
        gll16(bS + k1, &Bs[buf ^ 1][wbase]);
      }
      s16x8 af[4], bfr[2];
#pragma unroll
      for (int mf = 0; mf < 4; mf++)
        af[mf] = *(const s16x8*)&As[buf][(wm * 64 + mf * 16 + lrow) * 32 + fswz];
#pragma unroll
      for (int nf = 0; nf < 2; nf++)
        bfr[nf] = *(const s16x8*)&Bs[buf][(wn * 32 + nf * 16 + lrow) * 32 + fswz];
#pragma unroll
      for (int mf = 0; mf < 4; mf++)
#pragma unroll
        for (int nf = 0; nf < 2; nf++)
          acc[mf][nf] = __builtin_amdgcn_mfma_f32_16x16x32_bf16(af[mf], bfr[nf], acc[mf][nf], 0, 0, 0);
      asm volatile("s_waitcnt vmcnt(0)" ::: "memory");
      __syncthreads();
      buf ^= 1;
    }
#pragma unroll
    for (int mf = 0; mf < 4; mf++)
#pragma unroll
      for (int nf = 0; nf < 2; nf++) {
        const int col = n0 + wn * 32 + nf * 16 + lrow;
        const float bb = b2[e * C_DIM + col];
#pragma unroll
        for (int r = 0; r < 4; r++) {
          const int gr = wm * 64 + mf * 16 + lgrp * 4 + r;
          if (m0 + gr < cnt) {
            Out[(size_t)(hb + gr) * C_DIM + col] = acc[mf][nf][r] + bb;
          }
        }
      }
  }
}

// combine pairs + transpose to (B, C, HW)
__global__ __launch_bounds__(256) void k_combine(
    const float* __restrict__ Out, const int* __restrict__ offsets,
    const int* __restrict__ counts, const int* __restrict__ pairE,
    const int* __restrict__ pairPos, const float* __restrict__ pairW,
    float* __restrict__ out) {
  __shared__ float tile[32][33];
  const int b = blockIdx.z;
  const int c0 = blockIdx.y * 32;
  const int hw0 = blockIdx.x * 32;
  const int tx = threadIdx.x, ty = threadIdx.y;
#pragma unroll
  for (int i = 0; i < 4; i++) {
    const int n = b * HW + hw0 + ty + i * 8;
    float v = 0.f;
#pragma unroll
    for (int s = 0; s < 2; s++) {
      const int e = pairE[2 * n + s];
      if (e >= 0) {
        const int pos = pairPos[2 * n + s];
        if (pos < counts[e]) {
          const int idx = offsets[e] + pos;
          v += pairW[2 * n + s] * Out[(size_t)idx * C_DIM + c0 + tx];
        }
      }
    }
    tile[ty + i * 8][tx] = v;
  }
  __syncthreads();
#pragma unroll
  for (int i = 0; i < 4; i++) {
    out[((size_t)b * C_DIM + c0 + ty + i * 8) * HW + hw0 + tx] = tile[tx][ty + i * 8];
  }
}

extern "C" void kernel_launch(void* const* d_in, const int* in_sizes, int n_in,
                              void* d_out, int out_size, void* d_ws, size_t ws_size,
                              hipStream_t stream) {
  const float* x = (const float*)d_in[0];
  const float* noise = (const float*)d_in[1];
  const float* wg = (const float*)d_in[2];
  const float* bg = (const float*)d_in[3];
  const float* wn = (const float*)d_in[4];
  const float* bn = (const float*)d_in[5];
  const float* w1 = (const float*)d_in[6];
  const float* b1 = (const float*)d_in[7];
  const float* w2 = (const float*)d_in[8];
  const float* b2 = (const float*)d_in[9];
  const float* w3 = (const float*)d_in[10];
  const float* b3 = (const float*)d_in[11];
  float* out = (float*)d_out;

  char* ws = (char*)d_ws;
  float* xt = (float*)ws;                    ws += (size_t)N_TOK * C_DIM * 4;  // aliased as Out later
  float* Outb = xt;
  unsigned short* Xbf = (unsigned short*)ws; ws += (size_t)N_TOK * C_DIM * 2;
  unsigned short* w1t = (unsigned short*)ws; ws += (size_t)E_NUM * C_DIM * HID * 2;
  unsigned short* w3t = (unsigned short*)ws; ws += (size_t)E_NUM * C_DIM * HID * 2;
  unsigned short* w2t = (unsigned short*)ws; ws += (size_t)E_NUM * HID * C_DIM * 2;
  unsigned short* H = (unsigned short*)ws;   ws += (size_t)N_TOK * HID * 2;
  int* counts = (int*)ws;                    ws += 256;
  int* offsets = (int*)ws;                   ws += 256;
  int* tok_list = (int*)ws;                  ws += (size_t)E_NUM * N_TOK * 4;
  int* pairE = (int*)ws;                     ws += (size_t)N_TOK * 2 * 4;
  int* pairPos = (int*)ws;                   ws += (size_t)N_TOK * 2 * 4;
  float* pairW = (float*)ws;                 ws += (size_t)N_TOK * 2 * 4;

  hipMemsetAsync(counts, 0, 64, stream);

  k_transpose_in<<<dim3(HW / 32, C_DIM / 32, BATCH), dim3(32, 8), 0, stream>>>(x, xt, Xbf);
  k_prep_w<<<dim3(HID / 32, C_DIM / 32, E_NUM), dim3(32, 8), 0, stream>>>(w1, w1t, C_DIM, HID);
  k_prep_w<<<dim3(HID / 32, C_DIM / 32, E_NUM), dim3(32, 8), 0, stream>>>(w3, w3t, C_DIM, HID);
  k_prep_w<<<dim3(C_DIM / 32, HID / 32, E_NUM), dim3(32, 8), 0, stream>>>(w2, w2t, HID, C_DIM);
  k_gate<<<dim3(N_TOK / 4), dim3(256), 0, stream>>>(xt, noise, wg, bg, wn, bn,
                                                    counts, tok_list, pairE, pairPos, pairW);
  k_scan<<<1, 32, 0, stream>>>(counts, offsets);
  k_ffn_a<<<dim3(2048), dim3(256), 0, stream>>>(Xbf, w1t, b1, w3t, b3, counts, offsets,
                                                tok_list, H);
  k_ffn_b<<<dim3(2048), dim3(256), 0, stream>>>(H, w2t, b2, counts, offsets, Outb);
  k_combine<<<dim3(HW / 32, C_DIM / 32, BATCH), dim3(32, 8), 0, stream>>>(
      Outb, offsets, counts, pairE, pairPos, pairW, out);
}

// Round 4
// 374.791 us; speedup vs baseline: 3.3434x; 1.1614x over previous
//
#include <hip/hip_runtime.h>

#define BATCH 8
#define C_DIM 768
#define HW 2304
#define N_TOK 18432   // BATCH*HW
#define E_NUM 8
#define HID 1536

#define BM 128
#define MT (N_TOK / BM)          // 144 max M-tiles per expert
#define NT_A (HID / 64)          // 24 (BN=64, two B matrices)
#define NT_B (C_DIM / 64)        // 12 (BN=64)
#define NKA (C_DIM / 32)         // 24 K-steps pass A
#define NKB (HID / 32)           // 48 K-steps pass B

#define GT 64                    // gate: tokens per block

typedef short s16x8 __attribute__((ext_vector_type(8)));
typedef float f32x4 __attribute__((ext_vector_type(4)));

__device__ __forceinline__ unsigned short f2bf(float f) {
  unsigned int u = __float_as_uint(f);
  u = u + 0x7fffu + ((u >> 16) & 1u);
  return (unsigned short)(u >> 16);
}

// async global -> LDS, 16B per lane; LDS dest = wave-uniform base + lane*16
__device__ __forceinline__ void gll16(const unsigned short* g, unsigned short* l) {
  __builtin_amdgcn_global_load_lds(
      (const __attribute__((address_space(1))) unsigned int*)g,
      (__attribute__((address_space(3))) unsigned int*)l, 16, 0, 0);
}

// x (B, C, HW) -> Xbf (N, C) bf16  (fp32 xt no longer materialized)
__global__ __launch_bounds__(256) void k_convert_in(const float* __restrict__ x,
                                                    unsigned short* __restrict__ Xbf) {
  __shared__ float tile[32][33];
  const int b = blockIdx.z;
  const int c0 = blockIdx.y * 32;
  const int hw0 = blockIdx.x * 32;
  const int tx = threadIdx.x, ty = threadIdx.y;  // 32 x 8
  const float* xb = x + (size_t)b * C_DIM * HW;
#pragma unroll
  for (int i = 0; i < 4; i++) {
    tile[ty + i * 8][tx] = xb[(size_t)(c0 + ty + i * 8) * HW + hw0 + tx];
  }
  __syncthreads();
#pragma unroll
  for (int i = 0; i < 4; i++) {
    const size_t idx = (size_t)b * HW * C_DIM + (size_t)(hw0 + ty + i * 8) * C_DIM + c0 + tx;
    Xbf[idx] = f2bf(tile[tx][ty + i * 8]);
  }
}

// per-expert matrix transpose + bf16 convert: in (R,S) fp32 -> out (S,R) bf16
__global__ __launch_bounds__(256) void k_prep_w(const float* __restrict__ in,
                                                unsigned short* __restrict__ outT,
                                                int R, int S) {
  __shared__ float tile[32][33];
  const int e = blockIdx.z;
  const int s0 = blockIdx.x * 32, r0 = blockIdx.y * 32;
  const int tx = threadIdx.x, ty = threadIdx.y;
  const float* ip = in + (size_t)e * R * S;
  unsigned short* op = outT + (size_t)e * R * S;
#pragma unroll
  for (int i = 0; i < 4; i++) {
    tile[ty + i * 8][tx] = ip[(size_t)(r0 + ty + i * 8) * S + s0 + tx];
  }
  __syncthreads();
#pragma unroll
  for (int i = 0; i < 4; i++) {
    op[(size_t)(s0 + ty + i * 8) * R + r0 + tx] = f2bf(tile[tx][ty + i * 8]);
  }
}

// gating v2: block = 64 tokens (one b, 64 consecutive hw), 4 waves x 4 outputs.
// Reads x directly in (B,C,HW) layout -> LDS [c][hw] is a free transpose.
// Exact fp32 throughout (top-k flip risk forbids bf16 here).
__global__ __launch_bounds__(256) void k_gate(const float* __restrict__ x,
                                              const float* __restrict__ noise,
                                              const float* __restrict__ wg,
                                              const float* __restrict__ bg,
                                              const float* __restrict__ wn,
                                              const float* __restrict__ bn,
                                              int* __restrict__ counts,
                                              int* __restrict__ tok_list,
                                              int* __restrict__ pairE,
                                              int* __restrict__ pairPos,
                                              float* __restrict__ pairW) {
  __shared__ float Ws[C_DIM * 16];   // [k][e], e<8: gate, e>=8: noise
  __shared__ float Xs[GT][65];       // [c-local][hw-local], stride 65 -> conflict-free
  __shared__ float accS[GT][17];
  const int tid = threadIdx.x;
  const int lane = tid & 63;
  const int og = tid >> 6;           // wave id = output group (4 outputs each)
  const int n0 = blockIdx.x * GT;
  const int b = n0 / HW;
  const int hw0 = n0 % HW;           // HW % GT == 0, blocks never straddle b
  const float* xb = x + (size_t)b * C_DIM * HW + hw0;

  // stage W (once): wg cols 0..7, wn cols 8..15
  for (int idx = tid; idx < C_DIM * 8; idx += 256) {
    const int r = idx >> 3, c = idx & 7;
    Ws[r * 16 + c] = wg[idx];
    Ws[r * 16 + 8 + c] = wn[idx];
  }

  const int cl = tid >> 2, q = tid & 3;  // staging map: c-row, hw-quad
  float acc[4] = {};
  // preload chunk 0
  float4 xv[4];
#pragma unroll
  for (int i = 0; i < 4; i++)
    xv[i] = *(const float4*)(xb + (size_t)cl * HW + q * 16 + i * 4);

  for (int kc = 0; kc < C_DIM; kc += GT) {
    __syncthreads();  // Xs readers of prev chunk done (also covers Ws staging)
#pragma unroll
    for (int i = 0; i < 4; i++) {
      const int col = q * 16 + i * 4;
      Xs[cl][col + 0] = xv[i].x;
      Xs[cl][col + 1] = xv[i].y;
      Xs[cl][col + 2] = xv[i].z;
      Xs[cl][col + 3] = xv[i].w;
    }
    __syncthreads();
    if (kc + GT < C_DIM) {  // issue next chunk's loads before compute (T14)
#pragma unroll
      for (int i = 0; i < 4; i++)
        xv[i] = *(const float4*)(xb + (size_t)(kc + GT + cl) * HW + q * 16 + i * 4);
    }
#pragma unroll 16
    for (int k = 0; k < GT; k++) {
      const float xk = Xs[k][lane];
      const float4 wv = *(const float4*)&Ws[(kc + k) * 16 + og * 4];
      acc[0] = fmaf(xk, wv.x, acc[0]);
      acc[1] = fmaf(xk, wv.y, acc[1]);
      acc[2] = fmaf(xk, wv.z, acc[2]);
      acc[3] = fmaf(xk, wv.w, acc[3]);
    }
  }
#pragma unroll
  for (int j = 0; j < 4; j++) accS[lane][og * 4 + j] = acc[j];
  __syncthreads();

  if (og == 0) {  // 64 lanes handle 64 tokens in parallel
    const int n = n0 + lane;
    const float4 nz0 = *(const float4*)(noise + (size_t)n * 8);
    const float4 nz1 = *(const float4*)(noise + (size_t)n * 8 + 4);
    const float nzv[8] = {nz0.x, nz0.y, nz0.z, nz0.w, nz1.x, nz1.y, nz1.z, nz1.w};
    float noisy[E_NUM];
#pragma unroll
    for (int e = 0; e < E_NUM; e++) {
      const float lg = accS[lane][e] + bg[e];
      const float nl = accS[lane][8 + e] + bn[e];
      const float sp = (nl > 20.f) ? nl : log1pf(expf(nl));
      noisy[e] = lg + nzv[e] * sp;
    }
    int i0 = 0;
#pragma unroll
    for (int e = 1; e < E_NUM; e++) if (noisy[e] > noisy[i0]) i0 = e;
    int i1 = (i0 == 0) ? 1 : 0;
#pragma unroll
    for (int e = 0; e < E_NUM; e++) if (e != i0 && noisy[e] > noisy[i1]) i1 = e;
    const float v0 = noisy[i0], v1 = noisy[i1];
    const float e1 = expf(v1 - v0);
    const float z = 1.f + e1;
    const float p0 = (i0 == 0) ? (1.f / z) : ((i1 == 0) ? (e1 / z) : 0.f);
    const float p1 = (i0 == 1) ? (1.f / z) : ((i1 == 1) ? (e1 / z) : 0.f);
    if (p0 != 0.f) {
      const int pos = atomicAdd(&counts[i0], 1);
      tok_list[i0 * N_TOK + pos] = n;
      pairE[2 * n] = i0; pairPos[2 * n] = pos; pairW[2 * n] = p0;
    } else {
      pairE[2 * n] = -1;
    }
    if (p1 != 0.f) {
      const int pos = atomicAdd(&counts[i1], 1);
      tok_list[i1 * N_TOK + pos] = n;
      pairE[2 * n + 1] = i1; pairPos[2 * n + 1] = pos; pairW[2 * n + 1] = p1;
    } else {
      pairE[2 * n + 1] = -1;
    }
  }
}

__global__ void k_scan(int* __restrict__ counts, int* __restrict__ offsets) {
  if (threadIdx.x == 0) {
    int s = 0;
    for (int e = 0; e < E_NUM; e++) {
      offsets[e] = s;
      int c = counts[e];
      if (s + c > N_TOK) c = N_TOK - s;  // impossible statistically; OOB guard
      counts[e] = c;
      s += c;
    }
    offsets[E_NUM] = s;
  }
}

// pass A: H = silu(Xg@w1+b1) * (Xg@w3+b3)
// BM=128 x BN=64 (x2 mats), BK=32, global_load_lds + 2-phase prefetch,
// XOR chunk-swizzle (source side + read side; LDS stays linear [r][32]).
__global__ __launch_bounds__(256) void k_ffn_a(
    const unsigned short* __restrict__ Xbf, const unsigned short* __restrict__ w1t,
    const float* __restrict__ b1, const unsigned short* __restrict__ w3t,
    const float* __restrict__ b3, const int* __restrict__ counts,
    const int* __restrict__ offsets, const int* __restrict__ tok_list,
    unsigned short* __restrict__ H) {
  __shared__ __align__(16) unsigned short As[2][BM * 32];
  __shared__ __align__(16) unsigned short B1s[2][64 * 32];
  __shared__ __align__(16) unsigned short B3s[2][64 * 32];
  const int tid = threadIdx.x;
  const int lane = tid & 63;
  const int w = tid >> 6;
  const int wm = w >> 1, wn = w & 1;
  const int lrow = lane & 15, lgrp = lane >> 4;
  const int fswz = (lgrp ^ ((lrow >> 1) & 3)) << 3;   // read-side XOR (ushorts)
  const int r2 = tid >> 2;                            // staging row 0..63
  const int swz = ((tid & 3) ^ ((r2 >> 1) & 3)) << 3; // source-side XOR (ushorts)
  const int wbase = w << 9;                           // wave * 512 ushorts
  const int total = E_NUM * MT * NT_A;
  for (int vt = blockIdx.x; vt < total; vt += gridDim.x) {
    const int e = vt / (MT * NT_A);
    const int rem = vt - e * (MT * NT_A);
    const int tm = rem / NT_A;
    const int cnt = counts[e];
    const int m0 = tm * BM;
    if (m0 >= cnt) continue;
    const int tn = rem - tm * NT_A;
    const int n0 = tn * 64;
    int ga0 = m0 + r2;      if (ga0 > cnt - 1) ga0 = cnt - 1;
    int ga1 = m0 + 64 + r2; if (ga1 > cnt - 1) ga1 = cnt - 1;
    const unsigned short* aS0 = Xbf + (size_t)tok_list[e * N_TOK + ga0] * C_DIM + swz;
    const unsigned short* aS1 = Xbf + (size_t)tok_list[e * N_TOK + ga1] * C_DIM + swz;
    const unsigned short* b1S = w1t + ((size_t)e * HID + n0 + r2) * C_DIM + swz;
    const unsigned short* b3S = w3t + ((size_t)e * HID + n0 + r2) * C_DIM + swz;
    f32x4 acc1[4][2] = {};
    f32x4 acc3[4][2] = {};
    // prologue: stage K-step 0 into buf 0
    gll16(aS0, &As[0][wbase]);
    gll16(aS1, &As[0][2048 + wbase]);
    gll16(b1S, &B1s[0][wbase]);
    gll16(b3S, &B3s[0][wbase]);
    asm volatile("s_waitcnt vmcnt(0)" ::: "memory");
    __syncthreads();
    int buf = 0;
    for (int t = 0; t < NKA; ++t) {
      const int k1 = (t + 1) * 32;
      if (k1 < C_DIM) {  // stage next K-step into buf^1
        gll16(aS0 + k1, &As[buf ^ 1][wbase]);
        gll16(aS1 + k1, &As[buf ^ 1][2048 + wbase]);
        gll16(b1S + k1, &B1s[buf ^ 1][wbase]);
        gll16(b3S + k1, &B3s[buf ^ 1][wbase]);
      }
      s16x8 af[4], bf1[2], bf3[2];
#pragma unroll
      for (int mf = 0; mf < 4; mf++)
        af[mf] = *(const s16x8*)&As[buf][(wm * 64 + mf * 16 + lrow) * 32 + fswz];
#pragma unroll
      for (int nf = 0; nf < 2; nf++) {
        bf1[nf] = *(const s16x8*)&B1s[buf][(wn * 32 + nf * 16 + lrow) * 32 + fswz];
        bf3[nf] = *(const s16x8*)&B3s[buf][(wn * 32 + nf * 16 + lrow) * 32 + fswz];
      }
#pragma unroll
      for (int mf = 0; mf < 4; mf++)
#pragma unroll
        for (int nf = 0; nf < 2; nf++) {
          acc1[mf][nf] = __builtin_amdgcn_mfma_f32_16x16x32_bf16(af[mf], bf1[nf], acc1[mf][nf], 0, 0, 0);
          acc3[mf][nf] = __builtin_amdgcn_mfma_f32_16x16x32_bf16(af[mf], bf3[nf], acc3[mf][nf], 0, 0, 0);
        }
      asm volatile("s_waitcnt vmcnt(0)" ::: "memory");
      __syncthreads();
      buf ^= 1;
    }
    const int hb = offsets[e] + m0;
#pragma unroll
    for (int mf = 0; mf < 4; mf++)
#pragma unroll
      for (int nf = 0; nf < 2; nf++) {
        const int col = n0 + wn * 32 + nf * 16 + lrow;
        const float bb1 = b1[e * HID + col];
        const float bb3 = b3[e * HID + col];
#pragma unroll
        for (int r = 0; r < 4; r++) {
          const int gr = wm * 64 + mf * 16 + lgrp * 4 + r;
          if (m0 + gr < cnt) {
            const float g1 = acc1[mf][nf][r] + bb1;
            const float g3 = acc3[mf][nf][r] + bb3;
            const float hv = g1 / (1.f + expf(-g1)) * g3;
            H[(size_t)(hb + gr) * HID + col] = f2bf(hv);
          }
        }
      }
  }
}

// pass B: Out = H @ w2 + b2, BM=128 x BN=64, BK=32, same pipeline
__global__ __launch_bounds__(256) void k_ffn_b(
    const unsigned short* __restrict__ H, const unsigned short* __restrict__ w2t,
    const float* __restrict__ b2, const int* __restrict__ counts,
    const int* __restrict__ offsets, float* __restrict__ Out) {
  __shared__ __align__(16) unsigned short As[2][BM * 32];
  __shared__ __align__(16) unsigned short Bs[2][64 * 32];
  const int tid = threadIdx.x;
  const int lane = tid & 63;
  const int w = tid >> 6;
  const int wm = w >> 1, wn = w & 1;
  const int lrow = lane & 15, lgrp = lane >> 4;
  const int fswz = (lgrp ^ ((lrow >> 1) & 3)) << 3;
  const int r2 = tid >> 2;
  const int swz = ((tid & 3) ^ ((r2 >> 1) & 3)) << 3;
  const int wbase = w << 9;
  const int total = E_NUM * MT * NT_B;
  for (int vt = blockIdx.x; vt < total; vt += gridDim.x) {
    const int e = vt / (MT * NT_B);
    const int rem = vt - e * (MT * NT_B);
    const int tm = rem / NT_B;
    const int cnt = counts[e];
    const int m0 = tm * BM;
    if (m0 >= cnt) continue;
    const int tn = rem - tm * NT_B;
    const int n0 = tn * 64;
    const int hb = offsets[e] + m0;
    int ga0 = m0 + r2;      if (ga0 > cnt - 1) ga0 = cnt - 1;
    int ga1 = m0 + 64 + r2; if (ga1 > cnt - 1) ga1 = cnt - 1;
    const unsigned short* aS0 = H + (size_t)(offsets[e] + ga0) * HID + swz;
    const unsigned short* aS1 = H + (size_t)(offsets[e] + ga1) * HID + swz;
    const unsigned short* bS = w2t + ((size_t)e * C_DIM + n0 + r2) * HID + swz;
    f32x4 acc[4][2] = {};
    gll16(aS0, &As[0][wbase]);
    gll16(aS1, &As[0][2048 + wbase]);
    gll16(bS, &Bs[0][wbase]);
    asm volatile("s_waitcnt vmcnt(0)" ::: "memory");
    __syncthreads();
    int buf = 0;
    for (int t = 0; t < NKB; ++t) {
      const int k1 = (t + 1) * 32;
      if (k1 < HID) {
        gll16(aS0 + k1, &As[buf ^ 1][wbase]);
        gll16(aS1 + k1, &As[buf ^ 1][2048 + wbase]);
        gll16(bS + k1, &Bs[buf ^ 1][wbase]);
      }
      s16x8 af[4], bfr[2];
#pragma unroll
      for (int mf = 0; mf < 4; mf++)
        af[mf] = *(const s16x8*)&As[buf][(wm * 64 + mf * 16 + lrow) * 32 + fswz];
#pragma unroll
      for (int nf = 0; nf < 2; nf++)
        bfr[nf] = *(const s16x8*)&Bs[buf][(wn * 32 + nf * 16 + lrow) * 32 + fswz];
#pragma unroll
      for (int mf = 0; mf < 4; mf++)
#pragma unroll
        for (int nf = 0; nf < 2; nf++)
          acc[mf][nf] = __builtin_amdgcn_mfma_f32_16x16x32_bf16(af[mf], bfr[nf], acc[mf][nf], 0, 0, 0);
      asm volatile("s_waitcnt vmcnt(0)" ::: "memory");
      __syncthreads();
      buf ^= 1;
    }
#pragma unroll
    for (int mf = 0; mf < 4; mf++)
#pragma unroll
      for (int nf = 0; nf < 2; nf++) {
        const int col = n0 + wn * 32 + nf * 16 + lrow;
        const float bb = b2[e * C_DIM + col];
#pragma unroll
        for (int r = 0; r < 4; r++) {
          const int gr = wm * 64 + mf * 16 + lgrp * 4 + r;
          if (m0 + gr < cnt) {
            Out[(size_t)(hb + gr) * C_DIM + col] = acc[mf][nf][r] + bb;
          }
        }
      }
  }
}

// combine pairs + transpose to (B, C, HW)
__global__ __launch_bounds__(256) void k_combine(
    const float* __restrict__ Out, const int* __restrict__ offsets,
    const int* __restrict__ counts, const int* __restrict__ pairE,
    const int* __restrict__ pairPos, const float* __restrict__ pairW,
    float* __restrict__ out) {
  __shared__ float tile[32][33];
  const int b = blockIdx.z;
  const int c0 = blockIdx.y * 32;
  const int hw0 = blockIdx.x * 32;
  const int tx = threadIdx.x, ty = threadIdx.y;
#pragma unroll
  for (int i = 0; i < 4; i++) {
    const int n = b * HW + hw0 + ty + i * 8;
    float v = 0.f;
#pragma unroll
    for (int s = 0; s < 2; s++) {
      const int e = pairE[2 * n + s];
      if (e >= 0) {
        const int pos = pairPos[2 * n + s];
        if (pos < counts[e]) {
          const int idx = offsets[e] + pos;
          v += pairW[2 * n + s] * Out[(size_t)idx * C_DIM + c0 + tx];
        }
      }
    }
    tile[ty + i * 8][tx] = v;
  }
  __syncthreads();
#pragma unroll
  for (int i = 0; i < 4; i++) {
    out[((size_t)b * C_DIM + c0 + ty + i * 8) * HW + hw0 + tx] = tile[tx][ty + i * 8];
  }
}

extern "C" void kernel_launch(void* const* d_in, const int* in_sizes, int n_in,
                              void* d_out, int out_size, void* d_ws, size_t ws_size,
                              hipStream_t stream) {
  const float* x = (const float*)d_in[0];
  const float* noise = (const float*)d_in[1];
  const float* wg = (const float*)d_in[2];
  const float* bg = (const float*)d_in[3];
  const float* wn = (const float*)d_in[4];
  const float* bn = (const float*)d_in[5];
  const float* w1 = (const float*)d_in[6];
  const float* b1 = (const float*)d_in[7];
  const float* w2 = (const float*)d_in[8];
  const float* b2 = (const float*)d_in[9];
  const float* w3 = (const float*)d_in[10];
  const float* b3 = (const float*)d_in[11];
  float* out = (float*)d_out;

  char* ws = (char*)d_ws;
  float* Outb = (float*)ws;                  ws += (size_t)N_TOK * C_DIM * 4;
  unsigned short* Xbf = (unsigned short*)ws; ws += (size_t)N_TOK * C_DIM * 2;
  unsigned short* w1t = (unsigned short*)ws; ws += (size_t)E_NUM * C_DIM * HID * 2;
  unsigned short* w3t = (unsigned short*)ws; ws += (size_t)E_NUM * C_DIM * HID * 2;
  unsigned short* w2t = (unsigned short*)ws; ws += (size_t)E_NUM * HID * C_DIM * 2;
  unsigned short* H = (unsigned short*)ws;   ws += (size_t)N_TOK * HID * 2;
  int* counts = (int*)ws;                    ws += 256;
  int* offsets = (int*)ws;                   ws += 256;
  int* tok_list = (int*)ws;                  ws += (size_t)E_NUM * N_TOK * 4;
  int* pairE = (int*)ws;                     ws += (size_t)N_TOK * 2 * 4;
  int* pairPos = (int*)ws;                   ws += (size_t)N_TOK * 2 * 4;
  float* pairW = (float*)ws;                 ws += (size_t)N_TOK * 2 * 4;

  hipMemsetAsync(counts, 0, 64, stream);

  k_convert_in<<<dim3(HW / 32, C_DIM / 32, BATCH), dim3(32, 8), 0, stream>>>(x, Xbf);
  k_prep_w<<<dim3(HID / 32, C_DIM / 32, E_NUM), dim3(32, 8), 0, stream>>>(w1, w1t, C_DIM, HID);
  k_prep_w<<<dim3(HID / 32, C_DIM / 32, E_NUM), dim3(32, 8), 0, stream>>>(w3, w3t, C_DIM, HID);
  k_prep_w<<<dim3(C_DIM / 32, HID / 32, E_NUM), dim3(32, 8), 0, stream>>>(w2, w2t, HID, C_DIM);
  k_gate<<<dim3(N_TOK / GT), dim3(256), 0, stream>>>(x, noise, wg, bg, wn, bn,
                                                     counts, tok_list, pairE, pairPos, pairW);
  k_scan<<<1, 32, 0, stream>>>(counts, offsets);
  k_ffn_a<<<dim3(2048), dim3(256), 0, stream>>>(Xbf, w1t, b1, w3t, b3, counts, offsets,
                                                tok_list, H);
  k_ffn_b<<<dim3(2048), dim3(256), 0, stream>>>(H, w2t, b2, counts, offsets, Outb);
  k_combine<<<dim3(HW / 32, C_DIM / 32, BATCH), dim3(32, 8), 0, stream>>>(
      Outb, offsets, counts, pairE, pairPos, pairW, out);
}

// Round 5
// 349.687 us; speedup vs baseline: 3.5834x; 1.0718x over previous
//
#include <hip/hip_runtime.h>

#define BATCH 8
#define C_DIM 768
#define HW 2304
#define N_TOK 18432   // BATCH*HW
#define E_NUM 8
#define HID 1536

#define BM 128
#define NT_A (HID / 64)          // 24 (BN=64, two B matrices)
#define NT_B (C_DIM / 64)        // 12 (BN=64)
#define NKA (C_DIM / 32)         // 24 K-steps pass A
#define NKB (HID / 32)           // 48 K-steps pass B

#define GT 64                    // gate: tokens per block

typedef short s16x8 __attribute__((ext_vector_type(8)));
typedef float f32x4 __attribute__((ext_vector_type(4)));

__device__ __forceinline__ unsigned short f2bf(float f) {
  unsigned int u = __float_as_uint(f);
  u = u + 0x7fffu + ((u >> 16) & 1u);
  return (unsigned short)(u >> 16);
}

// async global -> LDS, 16B per lane; LDS dest = wave-uniform base + lane*16
__device__ __forceinline__ void gll16(const unsigned short* g, unsigned short* l) {
  __builtin_amdgcn_global_load_lds(
      (const __attribute__((address_space(1))) unsigned int*)g,
      (__attribute__((address_space(3))) unsigned int*)l, 16, 0, 0);
}

// x (B, C, HW) -> Xbf (N, C) bf16
__global__ __launch_bounds__(256) void k_convert_in(const float* __restrict__ x,
                                                    unsigned short* __restrict__ Xbf) {
  __shared__ float tile[32][33];
  const int b = blockIdx.z;
  const int c0 = blockIdx.y * 32;
  const int hw0 = blockIdx.x * 32;
  const int tx = threadIdx.x, ty = threadIdx.y;  // 32 x 8
  const float* xb = x + (size_t)b * C_DIM * HW;
#pragma unroll
  for (int i = 0; i < 4; i++) {
    tile[ty + i * 8][tx] = xb[(size_t)(c0 + ty + i * 8) * HW + hw0 + tx];
  }
  __syncthreads();
#pragma unroll
  for (int i = 0; i < 4; i++) {
    const size_t idx = (size_t)b * HW * C_DIM + (size_t)(hw0 + ty + i * 8) * C_DIM + c0 + tx;
    Xbf[idx] = f2bf(tile[tx][ty + i * 8]);
  }
}

// per-expert matrix transpose + bf16 convert: in (R,S) fp32 -> out (S,R) bf16
__global__ __launch_bounds__(256) void k_prep_w(const float* __restrict__ in,
                                                unsigned short* __restrict__ outT,
                                                int R, int S) {
  __shared__ float tile[32][33];
  const int e = blockIdx.z;
  const int s0 = blockIdx.x * 32, r0 = blockIdx.y * 32;
  const int tx = threadIdx.x, ty = threadIdx.y;
  const float* ip = in + (size_t)e * R * S;
  unsigned short* op = outT + (size_t)e * R * S;
#pragma unroll
  for (int i = 0; i < 4; i++) {
    tile[ty + i * 8][tx] = ip[(size_t)(r0 + ty + i * 8) * S + s0 + tx];
  }
  __syncthreads();
#pragma unroll
  for (int i = 0; i < 4; i++) {
    op[(size_t)(s0 + ty + i * 8) * R + r0 + tx] = f2bf(tile[tx][ty + i * 8]);
  }
}

// gating: block = 64 tokens, 4 waves x 4 outputs, exact fp32
__global__ __launch_bounds__(256) void k_gate(const float* __restrict__ x,
                                              const float* __restrict__ noise,
                                              const float* __restrict__ wg,
                                              const float* __restrict__ bg,
                                              const float* __restrict__ wn,
                                              const float* __restrict__ bn,
                                              int* __restrict__ counts,
                                              int* __restrict__ tok_list,
                                              int* __restrict__ pairE,
                                              int* __restrict__ pairPos,
                                              float* __restrict__ pairW) {
  __shared__ float Ws[C_DIM * 16];   // [k][e], e<8: gate, e>=8: noise
  __shared__ float Xs[GT][65];
  __shared__ float accS[GT][17];
  const int tid = threadIdx.x;
  const int lane = tid & 63;
  const int og = tid >> 6;
  const int n0 = blockIdx.x * GT;
  const int b = n0 / HW;
  const int hw0 = n0 % HW;
  const float* xb = x + (size_t)b * C_DIM * HW + hw0;

  for (int idx = tid; idx < C_DIM * 8; idx += 256) {
    const int r = idx >> 3, c = idx & 7;
    Ws[r * 16 + c] = wg[idx];
    Ws[r * 16 + 8 + c] = wn[idx];
  }

  const int cl = tid >> 2, q = tid & 3;
  float acc[4] = {};
  float4 xv[4];
#pragma unroll
  for (int i = 0; i < 4; i++)
    xv[i] = *(const float4*)(xb + (size_t)cl * HW + q * 16 + i * 4);

  for (int kc = 0; kc < C_DIM; kc += GT) {
    __syncthreads();
#pragma unroll
    for (int i = 0; i < 4; i++) {
      const int col = q * 16 + i * 4;
      Xs[cl][col + 0] = xv[i].x;
      Xs[cl][col + 1] = xv[i].y;
      Xs[cl][col + 2] = xv[i].z;
      Xs[cl][col + 3] = xv[i].w;
    }
    __syncthreads();
    if (kc + GT < C_DIM) {
#pragma unroll
      for (int i = 0; i < 4; i++)
        xv[i] = *(const float4*)(xb + (size_t)(kc + GT + cl) * HW + q * 16 + i * 4);
    }
#pragma unroll 16
    for (int k = 0; k < GT; k++) {
      const float xk = Xs[k][lane];
      const float4 wv = *(const float4*)&Ws[(kc + k) * 16 + og * 4];
      acc[0] = fmaf(xk, wv.x, acc[0]);
      acc[1] = fmaf(xk, wv.y, acc[1]);
      acc[2] = fmaf(xk, wv.z, acc[2]);
      acc[3] = fmaf(xk, wv.w, acc[3]);
    }
  }
#pragma unroll
  for (int j = 0; j < 4; j++) accS[lane][og * 4 + j] = acc[j];
  __syncthreads();

  if (og == 0) {
    const int n = n0 + lane;
    const float4 nz0 = *(const float4*)(noise + (size_t)n * 8);
    const float4 nz1 = *(const float4*)(noise + (size_t)n * 8 + 4);
    const float nzv[8] = {nz0.x, nz0.y, nz0.z, nz0.w, nz1.x, nz1.y, nz1.z, nz1.w};
    float noisy[E_NUM];
#pragma unroll
    for (int e = 0; e < E_NUM; e++) {
      const float lg = accS[lane][e] + bg[e];
      const float nl = accS[lane][8 + e] + bn[e];
      const float sp = (nl > 20.f) ? nl : log1pf(expf(nl));
      noisy[e] = lg + nzv[e] * sp;
    }
    int i0 = 0;
#pragma unroll
    for (int e = 1; e < E_NUM; e++) if (noisy[e] > noisy[i0]) i0 = e;
    int i1 = (i0 == 0) ? 1 : 0;
#pragma unroll
    for (int e = 0; e < E_NUM; e++) if (e != i0 && noisy[e] > noisy[i1]) i1 = e;
    const float v0 = noisy[i0], v1 = noisy[i1];
    const float e1 = expf(v1 - v0);
    const float z = 1.f + e1;
    const float p0 = (i0 == 0) ? (1.f / z) : ((i1 == 0) ? (e1 / z) : 0.f);
    const float p1 = (i0 == 1) ? (1.f / z) : ((i1 == 1) ? (e1 / z) : 0.f);
    if (p0 != 0.f) {
      const int pos = atomicAdd(&counts[i0], 1);
      tok_list[i0 * N_TOK + pos] = n;
      pairE[2 * n] = i0; pairPos[2 * n] = pos; pairW[2 * n] = p0;
    } else {
      pairE[2 * n] = -1;
    }
    if (p1 != 0.f) {
      const int pos = atomicAdd(&counts[i1], 1);
      tok_list[i1 * N_TOK + pos] = n;
      pairE[2 * n + 1] = i1; pairPos[2 * n + 1] = pos; pairW[2 * n + 1] = p1;
    } else {
      pairE[2 * n + 1] = -1;
    }
  }
}

// scan + active-tile prefix tables: tmap[0..8] = pass-A tile prefix, tmap[16..24] = pass-B
__global__ void k_scan(int* __restrict__ counts, int* __restrict__ offsets,
                       int* __restrict__ tmap) {
  if (threadIdx.x == 0) {
    int s = 0, ta = 0, tb = 0;
    for (int e = 0; e < E_NUM; e++) {
      offsets[e] = s;
      int c = counts[e];
      if (s + c > N_TOK) c = N_TOK - s;  // statistically impossible; OOB guard
      counts[e] = c;
      s += c;
      tmap[e] = ta; tmap[16 + e] = tb;
      const int mt = (c + BM - 1) / BM;
      ta += mt * NT_A;
      tb += mt * NT_B;
    }
    offsets[E_NUM] = s;
    tmap[8] = ta; tmap[24] = tb;
  }
}

// pass A: H = silu(Xg@w1+b1) * (Xg@w3+b3)
// BM=128 x BN=64 (x2 mats), BK=32; 4-buffer depth-3 pipeline, counted vmcnt,
// raw s_barrier (1/step); exact active-tile grid via tmap.
__global__ __launch_bounds__(256) void k_ffn_a(
    const unsigned short* __restrict__ Xbf, const unsigned short* __restrict__ w1t,
    const float* __restrict__ b1, const unsigned short* __restrict__ w3t,
    const float* __restrict__ b3, const int* __restrict__ counts,
    const int* __restrict__ offsets, const int* __restrict__ tok_list,
    const int* __restrict__ tmap, unsigned short* __restrict__ H) {
  __shared__ __align__(16) unsigned short As[4][BM * 32];   // 32 KB
  __shared__ __align__(16) unsigned short B1s[4][64 * 32];  // 16 KB
  __shared__ __align__(16) unsigned short B3s[4][64 * 32];  // 16 KB
  const int tid = threadIdx.x;
  const int lane = tid & 63;
  const int w = tid >> 6;
  const int wm = w >> 1, wn = w & 1;
  const int lrow = lane & 15, lgrp = lane >> 4;
  const int fswz = (lgrp ^ ((lrow >> 1) & 3)) << 3;
  const int r2 = tid >> 2;
  const int swz = ((tid & 3) ^ ((r2 >> 1) & 3)) << 3;
  const int wbase = w << 9;
  const int total = tmap[8];
  for (int vt = blockIdx.x; vt < total; vt += gridDim.x) {
    int e = 0;
#pragma unroll
    for (int i = 1; i < E_NUM; i++) if (vt >= tmap[i]) e = i;
    const int local = vt - tmap[e];
    const int tm = local / NT_A;
    const int tn = local - tm * NT_A;
    const int cnt = counts[e];
    const int m0 = tm * BM;
    const int n0 = tn * 64;
    int ga0 = m0 + r2;      if (ga0 > cnt - 1) ga0 = cnt - 1;
    int ga1 = m0 + 64 + r2; if (ga1 > cnt - 1) ga1 = cnt - 1;
    const unsigned short* aS0 = Xbf + (size_t)tok_list[e * N_TOK + ga0] * C_DIM + swz;
    const unsigned short* aS1 = Xbf + (size_t)tok_list[e * N_TOK + ga1] * C_DIM + swz;
    const unsigned short* b1S = w1t + ((size_t)e * HID + n0 + r2) * C_DIM + swz;
    const unsigned short* b3S = w3t + ((size_t)e * HID + n0 + r2) * C_DIM + swz;
    f32x4 acc1[4][2] = {};
    f32x4 acc3[4][2] = {};
#define STAGE_A(t_, b_)                          \
  do {                                           \
    const int ko_ = (t_) * 32;                   \
    gll16(aS0 + ko_, &As[b_][wbase]);            \
    gll16(aS1 + ko_, &As[b_][2048 + wbase]);     \
    gll16(b1S + ko_, &B1s[b_][wbase]);           \
    gll16(b3S + ko_, &B3s[b_][wbase]);           \
  } while (0)
    STAGE_A(0, 0); STAGE_A(1, 1); STAGE_A(2, 2);
    for (int t = 0; t < NKA; ++t) {
      if (t < NKA - 2)       asm volatile("s_waitcnt vmcnt(8)" ::: "memory");
      else if (t == NKA - 2) asm volatile("s_waitcnt vmcnt(4)" ::: "memory");
      else                   asm volatile("s_waitcnt vmcnt(0)" ::: "memory");
      __builtin_amdgcn_s_barrier();
      asm volatile("" ::: "memory");
      if (t + 3 < NKA) STAGE_A(t + 3, (t + 3) & 3);
      const int buf = t & 3;
      s16x8 af[4], bf1[2], bf3[2];
#pragma unroll
      for (int mf = 0; mf < 4; mf++)
        af[mf] = *(const s16x8*)&As[buf][(wm * 64 + mf * 16 + lrow) * 32 + fswz];
#pragma unroll
      for (int nf = 0; nf < 2; nf++) {
        bf1[nf] = *(const s16x8*)&B1s[buf][(wn * 32 + nf * 16 + lrow) * 32 + fswz];
        bf3[nf] = *(const s16x8*)&B3s[buf][(wn * 32 + nf * 16 + lrow) * 32 + fswz];
      }
#pragma unroll
      for (int mf = 0; mf < 4; mf++)
#pragma unroll
        for (int nf = 0; nf < 2; nf++) {
          acc1[mf][nf] = __builtin_amdgcn_mfma_f32_16x16x32_bf16(af[mf], bf1[nf], acc1[mf][nf], 0, 0, 0);
          acc3[mf][nf] = __builtin_amdgcn_mfma_f32_16x16x32_bf16(af[mf], bf3[nf], acc3[mf][nf], 0, 0, 0);
        }
    }
#undef STAGE_A
    const int hb = offsets[e] + m0;
#pragma unroll
    for (int mf = 0; mf < 4; mf++)
#pragma unroll
      for (int nf = 0; nf < 2; nf++) {
        const int col = n0 + wn * 32 + nf * 16 + lrow;
        const float bb1 = b1[e * HID + col];
        const float bb3 = b3[e * HID + col];
#pragma unroll
        for (int r = 0; r < 4; r++) {
          const int gr = wm * 64 + mf * 16 + lgrp * 4 + r;
          if (m0 + gr < cnt) {
            const float g1 = acc1[mf][nf][r] + bb1;
            const float g3 = acc3[mf][nf][r] + bb3;
            const float hv = g1 / (1.f + expf(-g1)) * g3;
            H[(size_t)(hb + gr) * HID + col] = f2bf(hv);
          }
        }
      }
  }
}

// pass B: Out = H @ w2 + b2, BM=128 x BN=64, BK=32, same pipeline (3 loads/step)
__global__ __launch_bounds__(256) void k_ffn_b(
    const unsigned short* __restrict__ H, const unsigned short* __restrict__ w2t,
    const float* __restrict__ b2, const int* __restrict__ counts,
    const int* __restrict__ offsets, const int* __restrict__ tmap,
    float* __restrict__ Out) {
  __shared__ __align__(16) unsigned short As[4][BM * 32];  // 32 KB
  __shared__ __align__(16) unsigned short Bs[4][64 * 32];  // 16 KB
  const int tid = threadIdx.x;
  const int lane = tid & 63;
  const int w = tid >> 6;
  const int wm = w >> 1, wn = w & 1;
  const int lrow = lane & 15, lgrp = lane >> 4;
  const int fswz = (lgrp ^ ((lrow >> 1) & 3)) << 3;
  const int r2 = tid >> 2;
  const int swz = ((tid & 3) ^ ((r2 >> 1) & 3)) << 3;
  const int wbase = w << 9;
  const int total = tmap[24];
  for (int vt = blockIdx.x; vt < total; vt += gridDim.x) {
    int e = 0;
#pragma unroll
    for (int i = 1; i < E_NUM; i++) if (vt >= tmap[16 + i]) e = i;
    const int local = vt - tmap[16 + e];
    const int tm = local / NT_B;
    const int tn = local - tm * NT_B;
    const int cnt = counts[e];
    const int m0 = tm * BM;
    const int n0 = tn * 64;
    const int hb = offsets[e] + m0;
    int ga0 = m0 + r2;      if (ga0 > cnt - 1) ga0 = cnt - 1;
    int ga1 = m0 + 64 + r2; if (ga1 > cnt - 1) ga1 = cnt - 1;
    const unsigned short* aS0 = H + (size_t)(offsets[e] + ga0) * HID + swz;
    const unsigned short* aS1 = H + (size_t)(offsets[e] + ga1) * HID + swz;
    const unsigned short* bS = w2t + ((size_t)e * C_DIM + n0 + r2) * HID + swz;
    f32x4 acc[4][2] = {};
#define STAGE_B(t_, b_)                          \
  do {                                           \
    const int ko_ = (t_) * 32;                   \
    gll16(aS0 + ko_, &As[b_][wbase]);            \
    gll16(aS1 + ko_, &As[b_][2048 + wbase]);     \
    gll16(bS + ko_, &Bs[b_][wbase]);             \
  } while (0)
    STAGE_B(0, 0); STAGE_B(1, 1); STAGE_B(2, 2);
    for (int t = 0; t < NKB; ++t) {
      if (t < NKB - 2)       asm volatile("s_waitcnt vmcnt(6)" ::: "memory");
      else if (t == NKB - 2) asm volatile("s_waitcnt vmcnt(3)" ::: "memory");
      else                   asm volatile("s_waitcnt vmcnt(0)" ::: "memory");
      __builtin_amdgcn_s_barrier();
      asm volatile("" ::: "memory");
      if (t + 3 < NKB) STAGE_B(t + 3, (t + 3) & 3);
      const int buf = t & 3;
      s16x8 af[4], bfr[2];
#pragma unroll
      for (int mf = 0; mf < 4; mf++)
        af[mf] = *(const s16x8*)&As[buf][(wm * 64 + mf * 16 + lrow) * 32 + fswz];
#pragma unroll
      for (int nf = 0; nf < 2; nf++)
        bfr[nf] = *(const s16x8*)&Bs[buf][(wn * 32 + nf * 16 + lrow) * 32 + fswz];
#pragma unroll
      for (int mf = 0; mf < 4; mf++)
#pragma unroll
        for (int nf = 0; nf < 2; nf++)
          acc[mf][nf] = __builtin_amdgcn_mfma_f32_16x16x32_bf16(af[mf], bfr[nf], acc[mf][nf], 0, 0, 0);
    }
#undef STAGE_B
#pragma unroll
    for (int mf = 0; mf < 4; mf++)
#pragma unroll
      for (int nf = 0; nf < 2; nf++) {
        const int col = n0 + wn * 32 + nf * 16 + lrow;
        const float bb = b2[e * C_DIM + col];
#pragma unroll
        for (int r = 0; r < 4; r++) {
          const int gr = wm * 64 + mf * 16 + lgrp * 4 + r;
          if (m0 + gr < cnt) {
            Out[(size_t)(hb + gr) * C_DIM + col] = acc[mf][nf][r] + bb;
          }
        }
      }
  }
}

// combine pairs + transpose to (B, C, HW)
__global__ __launch_bounds__(256) void k_combine(
    const float* __restrict__ Out, const int* __restrict__ offsets,
    const int* __restrict__ counts, const int* __restrict__ pairE,
    const int* __restrict__ pairPos, const float* __restrict__ pairW,
    float* __restrict__ out) {
  __shared__ float tile[32][33];
  const int b = blockIdx.z;
  const int c0 = blockIdx.y * 32;
  const int hw0 = blockIdx.x * 32;
  const int tx = threadIdx.x, ty = threadIdx.y;
#pragma unroll
  for (int i = 0; i < 4; i++) {
    const int n = b * HW + hw0 + ty + i * 8;
    float v = 0.f;
#pragma unroll
    for (int s = 0; s < 2; s++) {
      const int e = pairE[2 * n + s];
      if (e >= 0) {
        const int pos = pairPos[2 * n + s];
        if (pos < counts[e]) {
          const int idx = offsets[e] + pos;
          v += pairW[2 * n + s] * Out[(size_t)idx * C_DIM + c0 + tx];
        }
      }
    }
    tile[ty + i * 8][tx] = v;
  }
  __syncthreads();
#pragma unroll
  for (int i = 0; i < 4; i++) {
    out[((size_t)b * C_DIM + c0 + ty + i * 8) * HW + hw0 + tx] = tile[tx][ty + i * 8];
  }
}

extern "C" void kernel_launch(void* const* d_in, const int* in_sizes, int n_in,
                              void* d_out, int out_size, void* d_ws, size_t ws_size,
                              hipStream_t stream) {
  const float* x = (const float*)d_in[0];
  const float* noise = (const float*)d_in[1];
  const float* wg = (const float*)d_in[2];
  const float* bg = (const float*)d_in[3];
  const float* wn = (const float*)d_in[4];
  const float* bn = (const float*)d_in[5];
  const float* w1 = (const float*)d_in[6];
  const float* b1 = (const float*)d_in[7];
  const float* w2 = (const float*)d_in[8];
  const float* b2 = (const float*)d_in[9];
  const float* w3 = (const float*)d_in[10];
  const float* b3 = (const float*)d_in[11];
  float* out = (float*)d_out;

  char* ws = (char*)d_ws;
  float* Outb = (float*)ws;                  ws += (size_t)N_TOK * C_DIM * 4;
  unsigned short* Xbf = (unsigned short*)ws; ws += (size_t)N_TOK * C_DIM * 2;
  unsigned short* w1t = (unsigned short*)ws; ws += (size_t)E_NUM * C_DIM * HID * 2;
  unsigned short* w3t = (unsigned short*)ws; ws += (size_t)E_NUM * C_DIM * HID * 2;
  unsigned short* w2t = (unsigned short*)ws; ws += (size_t)E_NUM * HID * C_DIM * 2;
  unsigned short* H = (unsigned short*)ws;   ws += (size_t)N_TOK * HID * 2;
  int* counts = (int*)ws;                    ws += 256;
  int* offsets = (int*)ws;                   ws += 256;
  int* tmap = (int*)ws;                      ws += 256;
  int* tok_list = (int*)ws;                  ws += (size_t)E_NUM * N_TOK * 4;
  int* pairE = (int*)ws;                     ws += (size_t)N_TOK * 2 * 4;
  int* pairPos = (int*)ws;                   ws += (size_t)N_TOK * 2 * 4;
  float* pairW = (float*)ws;                 ws += (size_t)N_TOK * 2 * 4;

  hipMemsetAsync(counts, 0, 64, stream);

  k_convert_in<<<dim3(HW / 32, C_DIM / 32, BATCH), dim3(32, 8), 0, stream>>>(x, Xbf);
  k_prep_w<<<dim3(HID / 32, C_DIM / 32, E_NUM), dim3(32, 8), 0, stream>>>(w1, w1t, C_DIM, HID);
  k_prep_w<<<dim3(HID / 32, C_DIM / 32, E_NUM), dim3(32, 8), 0, stream>>>(w3, w3t, C_DIM, HID);
  k_prep_w<<<dim3(C_DIM / 32, HID / 32, E_NUM), dim3(32, 8), 0, stream>>>(w2, w2t, HID, C_DIM);
  k_gate<<<dim3(N_TOK / GT), dim3(256), 0, stream>>>(x, noise, wg, bg, wn, bn,
                                                     counts, tok_list, pairE, pairPos, pairW);
  k_scan<<<1, 32, 0, stream>>>(counts, offsets, tmap);
  k_ffn_a<<<dim3(2048), dim3(256), 0, stream>>>(Xbf, w1t, b1, w3t, b3, counts, offsets,
                                                tok_list, tmap, H);
  k_ffn_b<<<dim3(2048), dim3(256), 0, stream>>>(H, w2t, b2, counts, offsets, tmap, Outb);
  k_combine<<<dim3(HW / 32, C_DIM / 32, BATCH), dim3(32, 8), 0, stream>>>(
      Outb, offsets, counts, pairE, pairPos, pairW, out);
}

// Round 6
// 345.809 us; speedup vs baseline: 3.6236x; 1.0112x over previous
//
#include <hip/hip_runtime.h>

#define BATCH 8
#define C_DIM 768
#define HW 2304
#define N_TOK 18432   // BATCH*HW
#define E_NUM 8
#define HID 1536

#define BM 128
#define NT_A (HID / 64)          // 24 (BN=64, two B matrices)
#define NT_B (C_DIM / 64)        // 12 (BN=64)
#define NKA (C_DIM / 32)         // 24 K-steps pass A (divisible by 3)
#define NKB (HID / 32)           // 48 K-steps pass B (divisible by 3)

#define GT 64                    // gate: tokens per block

typedef short s16x8 __attribute__((ext_vector_type(8)));
typedef float f32x4 __attribute__((ext_vector_type(4)));

__device__ __forceinline__ unsigned short f2bf(float f) {
  unsigned int u = __float_as_uint(f);
  u = u + 0x7fffu + ((u >> 16) & 1u);
  return (unsigned short)(u >> 16);
}

// async global -> LDS, 16B per lane; LDS dest = wave-uniform base + lane*16
__device__ __forceinline__ void gll16(const unsigned short* g, unsigned short* l) {
  __builtin_amdgcn_global_load_lds(
      (const __attribute__((address_space(1))) unsigned int*)g,
      (__attribute__((address_space(3))) unsigned int*)l, 16, 0, 0);
}

// x (B, C, HW) -> Xbf (N, C) bf16
__global__ __launch_bounds__(256) void k_convert_in(const float* __restrict__ x,
                                                    unsigned short* __restrict__ Xbf) {
  __shared__ float tile[32][33];
  const int b = blockIdx.z;
  const int c0 = blockIdx.y * 32;
  const int hw0 = blockIdx.x * 32;
  const int tx = threadIdx.x, ty = threadIdx.y;  // 32 x 8
  const float* xb = x + (size_t)b * C_DIM * HW;
#pragma unroll
  for (int i = 0; i < 4; i++) {
    tile[ty + i * 8][tx] = xb[(size_t)(c0 + ty + i * 8) * HW + hw0 + tx];
  }
  __syncthreads();
#pragma unroll
  for (int i = 0; i < 4; i++) {
    const size_t idx = (size_t)b * HW * C_DIM + (size_t)(hw0 + ty + i * 8) * C_DIM + c0 + tx;
    Xbf[idx] = f2bf(tile[tx][ty + i * 8]);
  }
}

// per-expert matrix transpose + bf16 convert: in (R,S) fp32 -> out (S,R) bf16
__global__ __launch_bounds__(256) void k_prep_w(const float* __restrict__ in,
                                                unsigned short* __restrict__ outT,
                                                int R, int S) {
  __shared__ float tile[32][33];
  const int e = blockIdx.z;
  const int s0 = blockIdx.x * 32, r0 = blockIdx.y * 32;
  const int tx = threadIdx.x, ty = threadIdx.y;
  const float* ip = in + (size_t)e * R * S;
  unsigned short* op = outT + (size_t)e * R * S;
#pragma unroll
  for (int i = 0; i < 4; i++) {
    tile[ty + i * 8][tx] = ip[(size_t)(r0 + ty + i * 8) * S + s0 + tx];
  }
  __syncthreads();
#pragma unroll
  for (int i = 0; i < 4; i++) {
    op[(size_t)(s0 + ty + i * 8) * R + r0 + tx] = f2bf(tile[tx][ty + i * 8]);
  }
}

// gating: block = 64 tokens, 4 waves x 4 outputs, exact fp32
__global__ __launch_bounds__(256) void k_gate(const float* __restrict__ x,
                                              const float* __restrict__ noise,
                                              const float* __restrict__ wg,
                                              const float* __restrict__ bg,
                                              const float* __restrict__ wn,
                                              const float* __restrict__ bn,
                                              int* __restrict__ counts,
                                              int* __restrict__ tok_list,
                                              int* __restrict__ pairE,
                                              int* __restrict__ pairPos,
                                              float* __restrict__ pairW) {
  __shared__ float Ws[C_DIM * 16];   // [k][e], e<8: gate, e>=8: noise
  __shared__ float Xs[GT][65];
  __shared__ float accS[GT][17];
  const int tid = threadIdx.x;
  const int lane = tid & 63;
  const int og = tid >> 6;
  const int n0 = blockIdx.x * GT;
  const int b = n0 / HW;
  const int hw0 = n0 % HW;
  const float* xb = x + (size_t)b * C_DIM * HW + hw0;

  for (int idx = tid; idx < C_DIM * 8; idx += 256) {
    const int r = idx >> 3, c = idx & 7;
    Ws[r * 16 + c] = wg[idx];
    Ws[r * 16 + 8 + c] = wn[idx];
  }

  const int cl = tid >> 2, q = tid & 3;
  float acc[4] = {};
  float4 xv[4];
#pragma unroll
  for (int i = 0; i < 4; i++)
    xv[i] = *(const float4*)(xb + (size_t)cl * HW + q * 16 + i * 4);

  for (int kc = 0; kc < C_DIM; kc += GT) {
    __syncthreads();
#pragma unroll
    for (int i = 0; i < 4; i++) {
      const int col = q * 16 + i * 4;
      Xs[cl][col + 0] = xv[i].x;
      Xs[cl][col + 1] = xv[i].y;
      Xs[cl][col + 2] = xv[i].z;
      Xs[cl][col + 3] = xv[i].w;
    }
    __syncthreads();
    if (kc + GT < C_DIM) {
#pragma unroll
      for (int i = 0; i < 4; i++)
        xv[i] = *(const float4*)(xb + (size_t)(kc + GT + cl) * HW + q * 16 + i * 4);
    }
#pragma unroll 16
    for (int k = 0; k < GT; k++) {
      const float xk = Xs[k][lane];
      const float4 wv = *(const float4*)&Ws[(kc + k) * 16 + og * 4];
      acc[0] = fmaf(xk, wv.x, acc[0]);
      acc[1] = fmaf(xk, wv.y, acc[1]);
      acc[2] = fmaf(xk, wv.z, acc[2]);
      acc[3] = fmaf(xk, wv.w, acc[3]);
    }
  }
#pragma unroll
  for (int j = 0; j < 4; j++) accS[lane][og * 4 + j] = acc[j];
  __syncthreads();

  if (og == 0) {
    const int n = n0 + lane;
    const float4 nz0 = *(const float4*)(noise + (size_t)n * 8);
    const float4 nz1 = *(const float4*)(noise + (size_t)n * 8 + 4);
    const float nzv[8] = {nz0.x, nz0.y, nz0.z, nz0.w, nz1.x, nz1.y, nz1.z, nz1.w};
    float noisy[E_NUM];
#pragma unroll
    for (int e = 0; e < E_NUM; e++) {
      const float lg = accS[lane][e] + bg[e];
      const float nl = accS[lane][8 + e] + bn[e];
      const float sp = (nl > 20.f) ? nl : log1pf(expf(nl));
      noisy[e] = lg + nzv[e] * sp;
    }
    int i0 = 0;
#pragma unroll
    for (int e = 1; e < E_NUM; e++) if (noisy[e] > noisy[i0]) i0 = e;
    int i1 = (i0 == 0) ? 1 : 0;
#pragma unroll
    for (int e = 0; e < E_NUM; e++) if (e != i0 && noisy[e] > noisy[i1]) i1 = e;
    const float v0 = noisy[i0], v1 = noisy[i1];
    const float e1 = expf(v1 - v0);
    const float z = 1.f + e1;
    const float p0 = (i0 == 0) ? (1.f / z) : ((i1 == 0) ? (e1 / z) : 0.f);
    const float p1 = (i0 == 1) ? (1.f / z) : ((i1 == 1) ? (e1 / z) : 0.f);
    if (p0 != 0.f) {
      const int pos = atomicAdd(&counts[i0], 1);
      tok_list[i0 * N_TOK + pos] = n;
      pairE[2 * n] = i0; pairPos[2 * n] = pos; pairW[2 * n] = p0;
    } else {
      pairE[2 * n] = -1;
    }
    if (p1 != 0.f) {
      const int pos = atomicAdd(&counts[i1], 1);
      tok_list[i1 * N_TOK + pos] = n;
      pairE[2 * n + 1] = i1; pairPos[2 * n + 1] = pos; pairW[2 * n + 1] = p1;
    } else {
      pairE[2 * n + 1] = -1;
    }
  }
}

// scan + active-tile prefix tables: tmap[0..8] = pass-A tile prefix, tmap[16..24] = pass-B
__global__ void k_scan(int* __restrict__ counts, int* __restrict__ offsets,
                       int* __restrict__ tmap) {
  if (threadIdx.x == 0) {
    int s = 0, ta = 0, tb = 0;
    for (int e = 0; e < E_NUM; e++) {
      offsets[e] = s;
      int c = counts[e];
      if (s + c > N_TOK) c = N_TOK - s;  // statistically impossible; OOB guard
      counts[e] = c;
      s += c;
      tmap[e] = ta; tmap[16 + e] = tb;
      const int mt = (c + BM - 1) / BM;
      ta += mt * NT_A;
      tb += mt * NT_B;
    }
    offsets[E_NUM] = s;
    tmap[8] = ta; tmap[24] = tb;
  }
}

// compact routed token rows: Xg[r][:] = Xbf[tok_list[r]][:], contiguous per expert
__global__ __launch_bounds__(256) void k_compact(const unsigned short* __restrict__ Xbf,
                                                 const int* __restrict__ offsets,
                                                 const int* __restrict__ tok_list,
                                                 unsigned short* __restrict__ Xg) {
  const int total = offsets[E_NUM];
  const int half = threadIdx.x >> 7;   // 2 rows per block, 128 threads each
  const int lane = threadIdx.x & 127;
  for (int r = blockIdx.x * 2 + half; r < total; r += gridDim.x * 2) {
    int e = 0;
#pragma unroll
    for (int i = 1; i < E_NUM; i++) if (r >= offsets[i]) e = i;
    const int tok = tok_list[e * N_TOK + (r - offsets[e])];
    if (lane < 96) {  // 96 x 16B = 1536B = one row
      const uint4 v = ((const uint4*)(Xbf + (size_t)tok * C_DIM))[lane];
      ((uint4*)(Xg + (size_t)r * C_DIM))[lane] = v;
    }
  }
}

// pass A: H = silu(Xg@w1+b1) * (Xg@w3+b3)
// BM=128 x BN=64 (x2 mats), BK=32; contiguous compacted A; persistent grid,
// 3-buffer depth-2 counted-vmcnt pipeline, continuous across tiles.
__global__ __launch_bounds__(256, 3) void k_ffn_a(
    const unsigned short* __restrict__ Xg, const unsigned short* __restrict__ w1t,
    const float* __restrict__ b1, const unsigned short* __restrict__ w3t,
    const float* __restrict__ b3, const int* __restrict__ counts,
    const int* __restrict__ offsets, const int* __restrict__ tmap,
    unsigned short* __restrict__ H) {
  __shared__ __align__(16) unsigned short As[3][BM * 32];   // 24 KB
  __shared__ __align__(16) unsigned short B1s[3][64 * 32];  // 12 KB
  __shared__ __align__(16) unsigned short B3s[3][64 * 32];  // 12 KB
  const int tid = threadIdx.x;
  const int lane = tid & 63;
  const int w = tid >> 6;
  const int wm = w >> 1, wn = w & 1;
  const int lrow = lane & 15, lgrp = lane >> 4;
  const int fswz = (lgrp ^ ((lrow >> 1) & 3)) << 3;
  const int r2 = tid >> 2;
  const int swz = ((tid & 3) ^ ((r2 >> 1) & 3)) << 3;
  const int wbase = w << 9;
  const int total = tmap[8];
  int vt = blockIdx.x;
  if (vt >= total) return;

#define ADDR_A(VT_, E_, CNT_, M0_, N0_, A0_, A1_, P1_, P3_)              \
  {                                                                      \
    E_ = 0;                                                              \
    _Pragma("unroll") for (int i_ = 1; i_ < E_NUM; i_++)                 \
        if ((VT_) >= tmap[i_]) E_ = i_;                                  \
    const int local_ = (VT_) - tmap[E_];                                 \
    const int tm_ = local_ / NT_A;                                       \
    M0_ = tm_ * BM;                                                      \
    N0_ = (local_ - tm_ * NT_A) * 64;                                    \
    CNT_ = counts[E_];                                                   \
    A0_ = Xg + (size_t)(offsets[E_] + M0_ + r2) * C_DIM + swz;           \
    A1_ = A0_ + (size_t)64 * C_DIM;                                      \
    P1_ = w1t + ((size_t)E_ * HID + N0_ + r2) * C_DIM + swz;             \
    P3_ = w3t + ((size_t)E_ * HID + N0_ + r2) * C_DIM + swz;             \
  }

  int e, cnt, m0, n0;
  const unsigned short *a0, *a1, *p1, *p3;
  ADDR_A(vt, e, cnt, m0, n0, a0, a1, p1, p3);
  // prologue: stage steps 0,1 into bufs 0,1
  gll16(a0, &As[0][wbase]); gll16(a1, &As[0][2048 + wbase]);
  gll16(p1, &B1s[0][wbase]); gll16(p3, &B3s[0][wbase]);
  gll16(a0 + 32, &As[1][wbase]); gll16(a1 + 32, &As[1][2048 + wbase]);
  gll16(p1 + 32, &B1s[1][wbase]); gll16(p3 + 32, &B3s[1][wbase]);

#define STEP_A(T_, RB_, SB_)                                                        \
  {                                                                                 \
    const int t_ = (T_);                                                            \
    if (has_next || t_ < NKA - 1)                                                   \
      asm volatile("s_waitcnt vmcnt(4)" ::: "memory");                              \
    else                                                                            \
      asm volatile("s_waitcnt vmcnt(0)" ::: "memory");                              \
    __builtin_amdgcn_s_barrier();                                                   \
    asm volatile("" ::: "memory");                                                  \
    const int ts_ = t_ + 2;                                                         \
    if (ts_ < NKA) {                                                                \
      const int ko_ = ts_ * 32;                                                     \
      gll16(a0 + ko_, &As[SB_][wbase]); gll16(a1 + ko_, &As[SB_][2048 + wbase]);    \
      gll16(p1 + ko_, &B1s[SB_][wbase]); gll16(p3 + ko_, &B3s[SB_][wbase]);         \
    } else if (has_next) {                                                          \
      const int ko_ = (ts_ - NKA) * 32;                                             \
      gll16(na0 + ko_, &As[SB_][wbase]); gll16(na1 + ko_, &As[SB_][2048 + wbase]);  \
      gll16(np1 + ko_, &B1s[SB_][wbase]); gll16(np3 + ko_, &B3s[SB_][wbase]);       \
    }                                                                               \
    s16x8 af[4], bf1[2], bf3[2];                                                    \
    _Pragma("unroll") for (int mf = 0; mf < 4; mf++)                                \
        af[mf] = *(const s16x8*)&As[RB_][(wm * 64 + mf * 16 + lrow) * 32 + fswz];   \
    _Pragma("unroll") for (int nf = 0; nf < 2; nf++) {                              \
      bf1[nf] = *(const s16x8*)&B1s[RB_][(wn * 32 + nf * 16 + lrow) * 32 + fswz];   \
      bf3[nf] = *(const s16x8*)&B3s[RB_][(wn * 32 + nf * 16 + lrow) * 32 + fswz];   \
    }                                                                               \
    _Pragma("unroll") for (int mf = 0; mf < 4; mf++)                                \
      _Pragma("unroll") for (int nf = 0; nf < 2; nf++) {                            \
        acc1[mf][nf] = __builtin_amdgcn_mfma_f32_16x16x32_bf16(af[mf], bf1[nf], acc1[mf][nf], 0, 0, 0); \
        acc3[mf][nf] = __builtin_amdgcn_mfma_f32_16x16x32_bf16(af[mf], bf3[nf], acc3[mf][nf], 0, 0, 0); \
      }                                                                             \
  }

  while (true) {
    const int vt_next = vt + (int)gridDim.x;
    const bool has_next = vt_next < total;
    int ne, ncnt, nm0, nn0;
    const unsigned short *na0 = nullptr, *na1 = nullptr, *np1 = nullptr, *np3 = nullptr;
    if (has_next) ADDR_A(vt_next, ne, ncnt, nm0, nn0, na0, na1, np1, np3);
    f32x4 acc1[4][2] = {};
    f32x4 acc3[4][2] = {};
    for (int tt = 0; tt < NKA; tt += 3) {
      STEP_A(tt + 0, 0, 2);
      STEP_A(tt + 1, 1, 0);
      STEP_A(tt + 2, 2, 1);
    }
    const int hb = offsets[e] + m0;
#pragma unroll
    for (int mf = 0; mf < 4; mf++)
#pragma unroll
      for (int nf = 0; nf < 2; nf++) {
        const int col = n0 + wn * 32 + nf * 16 + lrow;
        const float bb1 = b1[e * HID + col];
        const float bb3 = b3[e * HID + col];
#pragma unroll
        for (int r = 0; r < 4; r++) {
          const int gr = wm * 64 + mf * 16 + lgrp * 4 + r;
          if (m0 + gr < cnt) {
            const float g1 = acc1[mf][nf][r] + bb1;
            const float g3 = acc3[mf][nf][r] + bb3;
            const float hv = g1 / (1.f + expf(-g1)) * g3;
            H[(size_t)(hb + gr) * HID + col] = f2bf(hv);
          }
        }
      }
    if (!has_next) break;
    vt = vt_next;
    e = ne; cnt = ncnt; m0 = nm0; n0 = nn0;
    a0 = na0; a1 = na1; p1 = np1; p3 = np3;
  }
#undef STEP_A
#undef ADDR_A
}

// pass B: Out = H @ w2 + b2, BM=128 x BN=64, BK=32, same persistent pipeline
__global__ __launch_bounds__(256, 3) void k_ffn_b(
    const unsigned short* __restrict__ H, const unsigned short* __restrict__ w2t,
    const float* __restrict__ b2, const int* __restrict__ counts,
    const int* __restrict__ offsets, const int* __restrict__ tmap,
    float* __restrict__ Out) {
  __shared__ __align__(16) unsigned short As[3][BM * 32];  // 24 KB
  __shared__ __align__(16) unsigned short Bs[3][64 * 32];  // 12 KB
  const int tid = threadIdx.x;
  const int lane = tid & 63;
  const int w = tid >> 6;
  const int wm = w >> 1, wn = w & 1;
  const int lrow = lane & 15, lgrp = lane >> 4;
  const int fswz = (lgrp ^ ((lrow >> 1) & 3)) << 3;
  const int r2 = tid >> 2;
  const int swz = ((tid & 3) ^ ((r2 >> 1) & 3)) << 3;
  const int wbase = w << 9;
  const int total = tmap[24];
  int vt = blockIdx.x;
  if (vt >= total) return;

#define ADDR_B(VT_, E_, CNT_, M0_, N0_, A0_, A1_, BP_)                   \
  {                                                                      \
    E_ = 0;                                                              \
    _Pragma("unroll") for (int i_ = 1; i_ < E_NUM; i_++)                 \
        if ((VT_) >= tmap[16 + i_]) E_ = i_;                             \
    const int local_ = (VT_) - tmap[16 + E_];                            \
    const int tm_ = local_ / NT_B;                                       \
    M0_ = tm_ * BM;                                                      \
    N0_ = (local_ - tm_ * NT_B) * 64;                                    \
    CNT_ = counts[E_];                                                   \
    A0_ = H + (size_t)(offsets[E_] + M0_ + r2) * HID + swz;              \
    A1_ = A0_ + (size_t)64 * HID;                                        \
    BP_ = w2t + ((size_t)E_ * C_DIM + N0_ + r2) * HID + swz;             \
  }

  int e, cnt, m0, n0;
  const unsigned short *a0, *a1, *bp;
  ADDR_B(vt, e, cnt, m0, n0, a0, a1, bp);
  gll16(a0, &As[0][wbase]); gll16(a1, &As[0][2048 + wbase]); gll16(bp, &Bs[0][wbase]);
  gll16(a0 + 32, &As[1][wbase]); gll16(a1 + 32, &As[1][2048 + wbase]); gll16(bp + 32, &Bs[1][wbase]);

#define STEP_B(T_, RB_, SB_)                                                        \
  {                                                                                 \
    const int t_ = (T_);                                                            \
    if (has_next || t_ < NKB - 1)                                                   \
      asm volatile("s_waitcnt vmcnt(3)" ::: "memory");                              \
    else                                                                            \
      asm volatile("s_waitcnt vmcnt(0)" ::: "memory");                              \
    __builtin_amdgcn_s_barrier();                                                   \
    asm volatile("" ::: "memory");                                                  \
    const int ts_ = t_ + 2;                                                         \
    if (ts_ < NKB) {                                                                \
      const int ko_ = ts_ * 32;                                                     \
      gll16(a0 + ko_, &As[SB_][wbase]); gll16(a1 + ko_, &As[SB_][2048 + wbase]);    \
      gll16(bp + ko_, &Bs[SB_][wbase]);                                             \
    } else if (has_next) {                                                          \
      const int ko_ = (ts_ - NKB) * 32;                                             \
      gll16(na0 + ko_, &As[SB_][wbase]); gll16(na1 + ko_, &As[SB_][2048 + wbase]);  \
      gll16(nbp + ko_, &Bs[SB_][wbase]);                                            \
    }                                                                               \
    s16x8 af[4], bfr[2];                                                            \
    _Pragma("unroll") for (int mf = 0; mf < 4; mf++)                                \
        af[mf] = *(const s16x8*)&As[RB_][(wm * 64 + mf * 16 + lrow) * 32 + fswz];   \
    _Pragma("unroll") for (int nf = 0; nf < 2; nf++)                                \
        bfr[nf] = *(const s16x8*)&Bs[RB_][(wn * 32 + nf * 16 + lrow) * 32 + fswz];  \
    _Pragma("unroll") for (int mf = 0; mf < 4; mf++)                                \
      _Pragma("unroll") for (int nf = 0; nf < 2; nf++)                              \
        acc[mf][nf] = __builtin_amdgcn_mfma_f32_16x16x32_bf16(af[mf], bfr[nf], acc[mf][nf], 0, 0, 0); \
  }

  while (true) {
    const int vt_next = vt + (int)gridDim.x;
    const bool has_next = vt_next < total;
    int ne, ncnt, nm0, nn0;
    const unsigned short *na0 = nullptr, *na1 = nullptr, *nbp = nullptr;
    if (has_next) ADDR_B(vt_next, ne, ncnt, nm0, nn0, na0, na1, nbp);
    f32x4 acc[4][2] = {};
    for (int tt = 0; tt < NKB; tt += 3) {
      STEP_B(tt + 0, 0, 2);
      STEP_B(tt + 1, 1, 0);
      STEP_B(tt + 2, 2, 1);
    }
    const int hb = offsets[e] + m0;
#pragma unroll
    for (int mf = 0; mf < 4; mf++)
#pragma unroll
      for (int nf = 0; nf < 2; nf++) {
        const int col = n0 + wn * 32 + nf * 16 + lrow;
        const float bb = b2[e * C_DIM + col];
#pragma unroll
        for (int r = 0; r < 4; r++) {
          const int gr = wm * 64 + mf * 16 + lgrp * 4 + r;
          if (m0 + gr < cnt) {
            Out[(size_t)(hb + gr) * C_DIM + col] = acc[mf][nf][r] + bb;
          }
        }
      }
    if (!has_next) break;
    vt = vt_next;
    e = ne; cnt = ncnt; m0 = nm0; n0 = nn0;
    a0 = na0; a1 = na1; bp = nbp;
  }
#undef STEP_B
#undef ADDR_B
}

// combine pairs + transpose to (B, C, HW)
__global__ __launch_bounds__(256) void k_combine(
    const float* __restrict__ Out, const int* __restrict__ offsets,
    const int* __restrict__ counts, const int* __restrict__ pairE,
    const int* __restrict__ pairPos, const float* __restrict__ pairW,
    float* __restrict__ out) {
  __shared__ float tile[32][33];
  const int b = blockIdx.z;
  const int c0 = blockIdx.y * 32;
  const int hw0 = blockIdx.x * 32;
  const int tx = threadIdx.x, ty = threadIdx.y;
#pragma unroll
  for (int i = 0; i < 4; i++) {
    const int n = b * HW + hw0 + ty + i * 8;
    float v = 0.f;
#pragma unroll
    for (int s = 0; s < 2; s++) {
      const int e = pairE[2 * n + s];
      if (e >= 0) {
        const int pos = pairPos[2 * n + s];
        if (pos < counts[e]) {
          const int idx = offsets[e] + pos;
          v += pairW[2 * n + s] * Out[(size_t)idx * C_DIM + c0 + tx];
        }
      }
    }
    tile[ty + i * 8][tx] = v;
  }
  __syncthreads();
#pragma unroll
  for (int i = 0; i < 4; i++) {
    out[((size_t)b * C_DIM + c0 + ty + i * 8) * HW + hw0 + tx] = tile[tx][ty + i * 8];
  }
}

extern "C" void kernel_launch(void* const* d_in, const int* in_sizes, int n_in,
                              void* d_out, int out_size, void* d_ws, size_t ws_size,
                              hipStream_t stream) {
  const float* x = (const float*)d_in[0];
  const float* noise = (const float*)d_in[1];
  const float* wg = (const float*)d_in[2];
  const float* bg = (const float*)d_in[3];
  const float* wn = (const float*)d_in[4];
  const float* bn = (const float*)d_in[5];
  const float* w1 = (const float*)d_in[6];
  const float* b1 = (const float*)d_in[7];
  const float* w2 = (const float*)d_in[8];
  const float* b2 = (const float*)d_in[9];
  const float* w3 = (const float*)d_in[10];
  const float* b3 = (const float*)d_in[11];
  float* out = (float*)d_out;

  char* ws = (char*)d_ws;
  float* Outb = (float*)ws;                  ws += (size_t)N_TOK * C_DIM * 4;
  unsigned short* Xbf = (unsigned short*)ws; ws += (size_t)N_TOK * C_DIM * 2;
  unsigned short* Xg = (unsigned short*)ws;  ws += (size_t)(N_TOK + BM) * C_DIM * 2;
  unsigned short* w1t = (unsigned short*)ws; ws += (size_t)E_NUM * C_DIM * HID * 2;
  unsigned short* w3t = (unsigned short*)ws; ws += (size_t)E_NUM * C_DIM * HID * 2;
  unsigned short* w2t = (unsigned short*)ws; ws += (size_t)E_NUM * HID * C_DIM * 2;
  unsigned short* H = (unsigned short*)ws;   ws += (size_t)N_TOK * HID * 2;
  int* counts = (int*)ws;                    ws += 256;
  int* offsets = (int*)ws;                   ws += 256;
  int* tmap = (int*)ws;                      ws += 256;
  int* tok_list = (int*)ws;                  ws += (size_t)E_NUM * N_TOK * 4;
  int* pairE = (int*)ws;                     ws += (size_t)N_TOK * 2 * 4;
  int* pairPos = (int*)ws;                   ws += (size_t)N_TOK * 2 * 4;
  float* pairW = (float*)ws;                 ws += (size_t)N_TOK * 2 * 4;

  hipMemsetAsync(counts, 0, 64, stream);

  k_convert_in<<<dim3(HW / 32, C_DIM / 32, BATCH), dim3(32, 8), 0, stream>>>(x, Xbf);
  k_prep_w<<<dim3(HID / 32, C_DIM / 32, E_NUM), dim3(32, 8), 0, stream>>>(w1, w1t, C_DIM, HID);
  k_prep_w<<<dim3(HID / 32, C_DIM / 32, E_NUM), dim3(32, 8), 0, stream>>>(w3, w3t, C_DIM, HID);
  k_prep_w<<<dim3(C_DIM / 32, HID / 32, E_NUM), dim3(32, 8), 0, stream>>>(w2, w2t, HID, C_DIM);
  k_gate<<<dim3(N_TOK / GT), dim3(256), 0, stream>>>(x, noise, wg, bg, wn, bn,
                                                     counts, tok_list, pairE, pairPos, pairW);
  k_scan<<<1, 32, 0, stream>>>(counts, offsets, tmap);
  k_compact<<<dim3(1024), dim3(256), 0, stream>>>(Xbf, offsets, tok_list, Xg);
  k_ffn_a<<<dim3(768), dim3(256), 0, stream>>>(Xg, w1t, b1, w3t, b3, counts, offsets,
                                               tmap, H);
  k_ffn_b<<<dim3(768), dim3(256), 0, stream>>>(H, w2t, b2, counts, offsets, tmap, Outb);
  k_combine<<<dim3(HW / 32, C_DIM / 32, BATCH), dim3(32, 8), 0, stream>>>(
      Outb, offsets, counts, pairE, pairPos, pairW, out);
}

// Round 7
// 301.116 us; speedup vs baseline: 4.1614x; 1.1484x over previous
//
#include <hip/hip_runtime.h>

#define BATCH 8
#define C_DIM 768
#define HW 2304
#define N_TOK 18432   // BATCH*HW
#define E_NUM 8
#define HID 1536

#define BM 128
#define NT_A (HID / 64)          // 24 n-tiles (BN=64, two B matrices)
#define NT_B (C_DIM / 128)       // 6 n-tiles  (BN=128)
#define NKA (C_DIM / 32)         // 24 K-steps pass A (div by 3)
#define NKB (HID / 32)           // 48 K-steps pass B (div by 3)
#define MAXROWS (N_TOK + 1024)   // padded routed-row capacity (152 panels)

#define GT 64                    // gate: tokens per block

typedef short s16x8 __attribute__((ext_vector_type(8)));
typedef unsigned short u16x8 __attribute__((ext_vector_type(8)));
typedef float f32x4 __attribute__((ext_vector_type(4)));

__device__ __forceinline__ unsigned short f2bf(float f) {
  unsigned int u = __float_as_uint(f);
  u = u + 0x7fffu + ((u >> 16) & 1u);
  return (unsigned short)(u >> 16);
}

// async global -> LDS, 16B per lane; LDS dest = wave-uniform base + lane*16
__device__ __forceinline__ void gll16(const unsigned short* g, unsigned short* l) {
  __builtin_amdgcn_global_load_lds(
      (const __attribute__((address_space(1))) unsigned int*)g,
      (__attribute__((address_space(3))) unsigned int*)l, 16, 0, 0);
}

// weights fp32 (R=K, S=N) -> packed bf16 panels:
// [e][n-panel][k-step][PROWS x 32k, 16B-chunk XOR by row]
__global__ __launch_bounds__(256) void k_prep_w(const float* __restrict__ in,
                                                unsigned short* __restrict__ outT,
                                                int R, int S, int NK, int PSH) {
  __shared__ float tile[32][33];
  const int e = blockIdx.z;
  const int s0 = blockIdx.x * 32, r0 = blockIdx.y * 32;
  const int tx = threadIdx.x, ty = threadIdx.y;
  const float* ip = in + (size_t)e * R * S;
  unsigned short* op = outT + (size_t)e * R * S;
#pragma unroll
  for (int i = 0; i < 4; i++) {
    tile[ty + i * 8][tx] = ip[(size_t)(r0 + ty + i * 8) * S + s0 + tx];
  }
  __syncthreads();
  const int t = r0 >> 5;
  const int q = tx >> 3;
#pragma unroll
  for (int i = 0; i < 4; i++) {
    const int s = s0 + ty + i * 8;
    const int nloc = s & ((1 << PSH) - 1);
    const int pn = s >> PSH;
    const int slot = q ^ ((nloc >> 1) & 3);
    op[(size_t)(pn * NK + t) * (32 << PSH) + nloc * 32 + (slot << 3) + (tx & 7)] =
        f2bf(tile[tx][ty + i * 8]);
  }
}

// gating: block = 64 tokens, 4 waves x 4 outputs, exact fp32; also emits Xbf (N,C) bf16
__global__ __launch_bounds__(256) void k_gate(const float* __restrict__ x,
                                              const float* __restrict__ noise,
                                              const float* __restrict__ wg,
                                              const float* __restrict__ bg,
                                              const float* __restrict__ wn,
                                              const float* __restrict__ bn,
                                              int* __restrict__ counts,
                                              int* __restrict__ tok_list,
                                              int* __restrict__ pairE,
                                              int* __restrict__ pairPos,
                                              float* __restrict__ pairW,
                                              unsigned short* __restrict__ Xbf) {
  __shared__ float Ws[C_DIM * 16];   // [k][e], e<8: gate, e>=8: noise
  __shared__ float Xs[GT][65];
  __shared__ float accS[GT][17];
  const int tid = threadIdx.x;
  const int lane = tid & 63;
  const int og = tid >> 6;
  const int n0 = blockIdx.x * GT;
  const int b = n0 / HW;
  const int hw0 = n0 % HW;
  const float* xb = x + (size_t)b * C_DIM * HW + hw0;

  for (int idx = tid; idx < C_DIM * 8; idx += 256) {
    const int r = idx >> 3, c = idx & 7;
    Ws[r * 16 + c] = wg[idx];
    Ws[r * 16 + 8 + c] = wn[idx];
  }

  const int cl = tid >> 2, q = tid & 3;
  const int xr = tid >> 2, xc = (tid & 3) << 4;
  float acc[4] = {};
  float4 xv[4];
#pragma unroll
  for (int i = 0; i < 4; i++)
    xv[i] = *(const float4*)(xb + (size_t)cl * HW + q * 16 + i * 4);

  for (int kc = 0; kc < C_DIM; kc += GT) {
    __syncthreads();
#pragma unroll
    for (int i = 0; i < 4; i++) {
      const int col = q * 16 + i * 4;
      Xs[cl][col + 0] = xv[i].x;
      Xs[cl][col + 1] = xv[i].y;
      Xs[cl][col + 2] = xv[i].z;
      Xs[cl][col + 3] = xv[i].w;
    }
    __syncthreads();
    if (kc + GT < C_DIM) {
#pragma unroll
      for (int i = 0; i < 4; i++)
        xv[i] = *(const float4*)(xb + (size_t)(kc + GT + cl) * HW + q * 16 + i * 4);
    }
    // emit Xbf chunk: row xr, 16 consecutive c at xc
    {
      u16x8 pa, pb;
#pragma unroll
      for (int j = 0; j < 8; j++) pa[j] = f2bf(Xs[xc + j][xr]);
#pragma unroll
      for (int j = 0; j < 8; j++) pb[j] = f2bf(Xs[xc + 8 + j][xr]);
      *(u16x8*)&Xbf[(size_t)(n0 + xr) * C_DIM + kc + xc] = pa;
      *(u16x8*)&Xbf[(size_t)(n0 + xr) * C_DIM + kc + xc + 8] = pb;
    }
#pragma unroll 16
    for (int k = 0; k < GT; k++) {
      const float xk = Xs[k][lane];
      const float4 wv = *(const float4*)&Ws[(kc + k) * 16 + og * 4];
      acc[0] = fmaf(xk, wv.x, acc[0]);
      acc[1] = fmaf(xk, wv.y, acc[1]);
      acc[2] = fmaf(xk, wv.z, acc[2]);
      acc[3] = fmaf(xk, wv.w, acc[3]);
    }
  }
#pragma unroll
  for (int j = 0; j < 4; j++) accS[lane][og * 4 + j] = acc[j];
  __syncthreads();

  if (og == 0) {
    const int n = n0 + lane;
    const float4 nz0 = *(const float4*)(noise + (size_t)n * 8);
    const float4 nz1 = *(const float4*)(noise + (size_t)n * 8 + 4);
    const float nzv[8] = {nz0.x, nz0.y, nz0.z, nz0.w, nz1.x, nz1.y, nz1.z, nz1.w};
    float noisy[E_NUM];
#pragma unroll
    for (int e = 0; e < E_NUM; e++) {
      const float lg = accS[lane][e] + bg[e];
      const float nl = accS[lane][8 + e] + bn[e];
      const float sp = (nl > 20.f) ? nl : log1pf(expf(nl));
      noisy[e] = lg + nzv[e] * sp;
    }
    int i0 = 0;
#pragma unroll
    for (int e = 1; e < E_NUM; e++) if (noisy[e] > noisy[i0]) i0 = e;
    int i1 = (i0 == 0) ? 1 : 0;
#pragma unroll
    for (int e = 0; e < E_NUM; e++) if (e != i0 && noisy[e] > noisy[i1]) i1 = e;
    const float v0 = noisy[i0], v1 = noisy[i1];
    const float e1 = expf(v1 - v0);
    const float z = 1.f + e1;
    const float p0 = (i0 == 0) ? (1.f / z) : ((i1 == 0) ? (e1 / z) : 0.f);
    const float p1 = (i0 == 1) ? (1.f / z) : ((i1 == 1) ? (e1 / z) : 0.f);
    if (p0 != 0.f) {
      const int pos = atomicAdd(&counts[i0], 1);
      tok_list[i0 * N_TOK + pos] = n;
      pairE[2 * n] = i0; pairPos[2 * n] = pos; pairW[2 * n] = p0;
    } else {
      pairE[2 * n] = -1;
    }
    if (p1 != 0.f) {
      const int pos = atomicAdd(&counts[i1], 1);
      tok_list[i1 * N_TOK + pos] = n;
      pairE[2 * n + 1] = i1; pairPos[2 * n + 1] = pos; pairW[2 * n + 1] = p1;
    } else {
      pairE[2 * n + 1] = -1;
    }
  }
}

// scan: 128-aligned per-expert offsets + active-tile prefix tables
__global__ void k_scan(int* __restrict__ counts, int* __restrict__ offsets,
                       int* __restrict__ tmap) {
  if (threadIdx.x == 0) {
    int s = 0, ta = 0, tb = 0;
    for (int e = 0; e < E_NUM; e++) {
      offsets[e] = s;
      int c = counts[e];
      if (c > N_TOK - s) c = (N_TOK - s > 0) ? (N_TOK - s) : 0;  // defensive cap
      counts[e] = c;
      tmap[e] = ta; tmap[16 + e] = tb;
      const int mt = (c + BM - 1) / BM;
      s += mt * BM;          // padded, 128-aligned
      ta += mt * NT_A;
      tb += mt * NT_B;
    }
    offsets[E_NUM] = s;
    tmap[8] = ta; tmap[24] = tb;
  }
}

// gather routed rows into packed A-panels: [panel][k-step][128 x 32k, chunk-XOR]
__global__ __launch_bounds__(256) void k_compact(const unsigned short* __restrict__ Xbf,
                                                 const int* __restrict__ offsets,
                                                 const int* __restrict__ counts,
                                                 const int* __restrict__ tok_list,
                                                 unsigned short* __restrict__ Xg) {
  const int total = offsets[E_NUM];  // padded
  const int half = threadIdx.x >> 7;
  const int lane = threadIdx.x & 127;
  for (int r = blockIdx.x * 2 + half; r < total; r += gridDim.x * 2) {
    int e = 0;
#pragma unroll
    for (int i = 1; i < E_NUM; i++) if (r >= offsets[i]) e = i;
    int pos = r - offsets[e];
    if (pos >= counts[e]) pos = counts[e] - 1;  // padding rows duplicate last row
    const int tok = tok_list[e * N_TOK + pos];
    if (lane < 96) {
      const int t = lane >> 2, q = lane & 3;
      const uint4 v = ((const uint4*)(Xbf + (size_t)tok * C_DIM))[lane];
      const int r7 = r & 127;
      const int slot = q ^ ((r7 >> 1) & 3);
      *(uint4*)(Xg + (size_t)((r >> 7) * NKA + t) * 4096 + r7 * 32 + (slot << 3)) = v;
    }
  }
}

// pass A: H = silu(Xg@w1+b1) * (Xg@w3+b3); packed panels, persistent,
// 3-buffer counted-vmcnt pipeline continuous across tiles; H written packed.
__global__ __launch_bounds__(256, 3) void k_ffn_a(
    const unsigned short* __restrict__ Xg, const unsigned short* __restrict__ w1t,
    const float* __restrict__ b1, const unsigned short* __restrict__ w3t,
    const float* __restrict__ b3, const int* __restrict__ offsets,
    const int* __restrict__ tmap, unsigned short* __restrict__ H) {
  __shared__ __align__(16) unsigned short As[3][BM * 32];   // 24 KB
  __shared__ __align__(16) unsigned short B1s[3][64 * 32];  // 12 KB
  __shared__ __align__(16) unsigned short B3s[3][64 * 32];  // 12 KB
  const int tid = threadIdx.x;
  const int lane = tid & 63;
  const int w = tid >> 6;
  const int wm = w >> 1, wn = w & 1;
  const int lrow = lane & 15, lgrp = lane >> 4;
  const int fswz = (lgrp ^ ((lrow >> 1) & 3)) << 3;
  const int wbase = w << 9;
  const int l8 = tid << 3;   // per-lane 16B offset (shorts)
  const int total = tmap[8];
  int vt = blockIdx.x;
  if (vt >= total) return;

#define ADDR_A(VT_, E_, HB_, N0_, AP_, P1_, P3_)                              \
  {                                                                           \
    E_ = 0;                                                                   \
    _Pragma("unroll") for (int i_ = 1; i_ < E_NUM; i_++)                      \
        if ((VT_) >= tmap[i_]) E_ = i_;                                       \
    const int local_ = (VT_) - tmap[E_];                                      \
    const int tm_ = local_ / NT_A;                                            \
    N0_ = (local_ - tm_ * NT_A) * 64;                                         \
    HB_ = offsets[E_] + tm_ * BM;                                             \
    AP_ = Xg + (size_t)(HB_ >> 7) * (NKA * 4096) + l8;                        \
    P1_ = w1t + (size_t)E_ * (C_DIM * HID) + (size_t)((N0_ >> 6) * NKA) * 2048 + l8; \
    P3_ = w3t + (size_t)E_ * (C_DIM * HID) + (size_t)((N0_ >> 6) * NKA) * 2048 + l8; \
  }

#define STAGE_A(AP_, P1_, P3_, TS_, SB_)                                      \
  {                                                                           \
    gll16(AP_ + (TS_) * 4096,        &As[SB_][wbase]);                        \
    gll16(AP_ + (TS_) * 4096 + 2048, &As[SB_][2048 + wbase]);                 \
    gll16(P1_ + (TS_) * 2048, &B1s[SB_][wbase]);                              \
    gll16(P3_ + (TS_) * 2048, &B3s[SB_][wbase]);                              \
  }

#define STEP_A(T_, RB_, SB_)                                                  \
  {                                                                           \
    if (has_next || (T_) < NKA - 1)                                           \
      asm volatile("s_waitcnt vmcnt(4)" ::: "memory");                        \
    else                                                                      \
      asm volatile("s_waitcnt vmcnt(0)" ::: "memory");                        \
    __builtin_amdgcn_s_barrier();                                             \
    asm volatile("" ::: "memory");                                            \
    const int ts_ = (T_) + 2;                                                 \
    if (ts_ < NKA) {                                                          \
      STAGE_A(aP, p1P, p3P, ts_, SB_);                                        \
    } else if (has_next) {                                                    \
      STAGE_A(naP, np1P, np3P, ts_ - NKA, SB_);                               \
    }                                                                         \
    s16x8 af[4], bf1[2], bf3[2];                                              \
    _Pragma("unroll") for (int mf = 0; mf < 4; mf++)                          \
        af[mf] = *(const s16x8*)&As[RB_][(wm * 64 + mf * 16 + lrow) * 32 + fswz]; \
    _Pragma("unroll") for (int nf = 0; nf < 2; nf++) {                        \
      bf1[nf] = *(const s16x8*)&B1s[RB_][(wn * 32 + nf * 16 + lrow) * 32 + fswz]; \
      bf3[nf] = *(const s16x8*)&B3s[RB_][(wn * 32 + nf * 16 + lrow) * 32 + fswz]; \
    }                                                                         \
    __builtin_amdgcn_s_setprio(1);                                            \
    _Pragma("unroll") for (int mf = 0; mf < 4; mf++)                          \
      _Pragma("unroll") for (int nf = 0; nf < 2; nf++) {                      \
        acc1[mf][nf] = __builtin_amdgcn_mfma_f32_16x16x32_bf16(af[mf], bf1[nf], acc1[mf][nf], 0, 0, 0); \
        acc3[mf][nf] = __builtin_amdgcn_mfma_f32_16x16x32_bf16(af[mf], bf3[nf], acc3[mf][nf], 0, 0, 0); \
      }                                                                       \
    __builtin_amdgcn_s_setprio(0);                                            \
  }

  int e, hb, n0;
  const unsigned short *aP, *p1P, *p3P;
  ADDR_A(vt, e, hb, n0, aP, p1P, p3P);
  STAGE_A(aP, p1P, p3P, 0, 0);
  STAGE_A(aP, p1P, p3P, 1, 1);

  while (true) {
    const int vt_next = vt + (int)gridDim.x;
    const bool has_next = vt_next < total;
    int ne = 0, nhb = 0, nn0 = 0;
    const unsigned short *naP = nullptr, *np1P = nullptr, *np3P = nullptr;
    if (has_next) ADDR_A(vt_next, ne, nhb, nn0, naP, np1P, np3P);
    f32x4 acc1[4][2] = {};
    f32x4 acc3[4][2] = {};
    for (int tt = 0; tt < NKA; tt += 3) {
      STEP_A(tt + 0, 0, 2);
      STEP_A(tt + 1, 1, 0);
      STEP_A(tt + 2, 2, 1);
    }
    const int Ph = hb >> 7;
#pragma unroll
    for (int mf = 0; mf < 4; mf++)
#pragma unroll
      for (int nf = 0; nf < 2; nf++) {
        const int col = n0 + wn * 32 + nf * 16 + lrow;
        const float bb1 = b1[e * HID + col];
        const float bb3 = b3[e * HID + col];
        const int th = col >> 5;
        const int kq = (col & 31) >> 3;
        const int ko = col & 7;
        unsigned short* hp = H + (size_t)(Ph * NKB + th) * 4096 + ko;
#pragma unroll
        for (int r = 0; r < 4; r++) {
          const int gr = wm * 64 + mf * 16 + lgrp * 4 + r;
          const float g1 = acc1[mf][nf][r] + bb1;
          const float g3 = acc3[mf][nf][r] + bb3;
          const float hv = g1 / (1.f + expf(-g1)) * g3;
          hp[gr * 32 + ((kq ^ ((gr >> 1) & 3)) << 3)] = f2bf(hv);
        }
      }
    if (!has_next) break;
    vt = vt_next;
    e = ne; hb = nhb; n0 = nn0;
    aP = naP; p1P = np1P; p3P = np3P;
  }
#undef STEP_A
#undef STAGE_A
#undef ADDR_A
}

// pass B: Out = H @ w2 + b2; BM=128 x BN=128, packed panels, same pipeline
__global__ __launch_bounds__(256, 3) void k_ffn_b(
    const unsigned short* __restrict__ H, const unsigned short* __restrict__ w2t,
    const float* __restrict__ b2, const int* __restrict__ offsets,
    const int* __restrict__ tmap, float* __restrict__ Out) {
  __shared__ __align__(16) unsigned short As[3][BM * 32];   // 24 KB
  __shared__ __align__(16) unsigned short Bs[3][128 * 32];  // 24 KB
  const int tid = threadIdx.x;
  const int lane = tid & 63;
  const int w = tid >> 6;
  const int wm = w >> 1, wn = w & 1;
  const int lrow = lane & 15, lgrp = lane >> 4;
  const int fswz = (lgrp ^ ((lrow >> 1) & 3)) << 3;
  const int wbase = w << 9;
  const int l8 = tid << 3;
  const int total = tmap[24];
  int vt = blockIdx.x;
  if (vt >= total) return;

#define ADDR_B(VT_, E_, HB_, N0_, AP_, BP_)                                   \
  {                                                                           \
    E_ = 0;                                                                   \
    _Pragma("unroll") for (int i_ = 1; i_ < E_NUM; i_++)                      \
        if ((VT_) >= tmap[16 + i_]) E_ = i_;                                  \
    const int local_ = (VT_) - tmap[16 + E_];                                 \
    const int tm_ = local_ / NT_B;                                            \
    N0_ = (local_ - tm_ * NT_B) * 128;                                        \
    HB_ = offsets[E_] + tm_ * BM;                                             \
    AP_ = H + (size_t)(HB_ >> 7) * (NKB * 4096) + l8;                         \
    BP_ = w2t + (size_t)E_ * (HID * C_DIM) + (size_t)((N0_ >> 7) * NKB) * 4096 + l8; \
  }

#define STAGE_B(AP_, BP_, TS_, SB_)                                           \
  {                                                                           \
    gll16(AP_ + (TS_) * 4096,        &As[SB_][wbase]);                        \
    gll16(AP_ + (TS_) * 4096 + 2048, &As[SB_][2048 + wbase]);                 \
    gll16(BP_ + (TS_) * 4096,        &Bs[SB_][wbase]);                        \
    gll16(BP_ + (TS_) * 4096 + 2048, &Bs[SB_][2048 + wbase]);                 \
  }

#define STEP_B(T_, RB_, SB_)                                                  \
  {                                                                           \
    if (has_next || (T_) < NKB - 1)                                           \
      asm volatile("s_waitcnt vmcnt(4)" ::: "memory");                        \
    else                                                                      \
      asm volatile("s_waitcnt vmcnt(0)" ::: "memory");                        \
    __builtin_amdgcn_s_barrier();                                             \
    asm volatile("" ::: "memory");                                            \
    const int ts_ = (T_) + 2;                                                 \
    if (ts_ < NKB) {                                                          \
      STAGE_B(aP, bP, ts_, SB_);                                              \
    } else if (has_next) {                                                    \
      STAGE_B(naP, nbP, ts_ - NKB, SB_);                                      \
    }                                                                         \
    s16x8 af[4], bfr[4];                                                      \
    _Pragma("unroll") for (int mf = 0; mf < 4; mf++)                          \
        af[mf] = *(const s16x8*)&As[RB_][(wm * 64 + mf * 16 + lrow) * 32 + fswz]; \
    _Pragma("unroll") for (int nf = 0; nf < 4; nf++)                          \
        bfr[nf] = *(const s16x8*)&Bs[RB_][(wn * 64 + nf * 16 + lrow) * 32 + fswz]; \
    __builtin_amdgcn_s_setprio(1);                                            \
    _Pragma("unroll") for (int mf = 0; mf < 4; mf++)                          \
      _Pragma("unroll") for (int nf = 0; nf < 4; nf++)                        \
        acc[mf][nf] = __builtin_amdgcn_mfma_f32_16x16x32_bf16(af[mf], bfr[nf], acc[mf][nf], 0, 0, 0); \
    __builtin_amdgcn_s_setprio(0);                                            \
  }

  int e, hb, n0;
  const unsigned short *aP, *bP;
  ADDR_B(vt, e, hb, n0, aP, bP);
  STAGE_B(aP, bP, 0, 0);
  STAGE_B(aP, bP, 1, 1);

  while (true) {
    const int vt_next = vt + (int)gridDim.x;
    const bool has_next = vt_next < total;
    int ne = 0, nhb = 0, nn0 = 0;
    const unsigned short *naP = nullptr, *nbP = nullptr;
    if (has_next) ADDR_B(vt_next, ne, nhb, nn0, naP, nbP);
    f32x4 acc[4][4] = {};
    for (int tt = 0; tt < NKB; tt += 3) {
      STEP_B(tt + 0, 0, 2);
      STEP_B(tt + 1, 1, 0);
      STEP_B(tt + 2, 2, 1);
    }
#pragma unroll
    for (int mf = 0; mf < 4; mf++)
#pragma unroll
      for (int nf = 0; nf < 4; nf++) {
        const int col = n0 + wn * 64 + nf * 16 + lrow;
        const float bb = b2[e * C_DIM + col];
#pragma unroll
        for (int r = 0; r < 4; r++) {
          const int gr = wm * 64 + mf * 16 + lgrp * 4 + r;
          Out[(size_t)(hb + gr) * C_DIM + col] = acc[mf][nf][r] + bb;
        }
      }
    if (!has_next) break;
    vt = vt_next;
    e = ne; hb = nhb; n0 = nn0;
    aP = naP; bP = nbP;
  }
#undef STEP_B
#undef STAGE_B
#undef ADDR_B
}

// combine pairs + transpose to (B, C, HW)
__global__ __launch_bounds__(256) void k_combine(
    const float* __restrict__ Out, const int* __restrict__ offsets,
    const int* __restrict__ counts, const int* __restrict__ pairE,
    const int* __restrict__ pairPos, const float* __restrict__ pairW,
    float* __restrict__ out) {
  __shared__ float tile[32][33];
  const int b = blockIdx.z;
  const int c0 = blockIdx.y * 32;
  const int hw0 = blockIdx.x * 32;
  const int tx = threadIdx.x, ty = threadIdx.y;
#pragma unroll
  for (int i = 0; i < 4; i++) {
    const int n = b * HW + hw0 + ty + i * 8;
    float v = 0.f;
#pragma unroll
    for (int s = 0; s < 2; s++) {
      const int e = pairE[2 * n + s];
      if (e >= 0) {
        const int pos = pairPos[2 * n + s];
        if (pos < counts[e]) {
          const int idx = offsets[e] + pos;
          v += pairW[2 * n + s] * Out[(size_t)idx * C_DIM + c0 + tx];
        }
      }
    }
    tile[ty + i * 8][tx] = v;
  }
  __syncthreads();
#pragma unroll
  for (int i = 0; i < 4; i++) {
    out[((size_t)b * C_DIM + c0 + ty + i * 8) * HW + hw0 + tx] = tile[tx][ty + i * 8];
  }
}

extern "C" void kernel_launch(void* const* d_in, const int* in_sizes, int n_in,
                              void* d_out, int out_size, void* d_ws, size_t ws_size,
                              hipStream_t stream) {
  const float* x = (const float*)d_in[0];
  const float* noise = (const float*)d_in[1];
  const float* wg = (const float*)d_in[2];
  const float* bg = (const float*)d_in[3];
  const float* wn = (const float*)d_in[4];
  const float* bn = (const float*)d_in[5];
  const float* w1 = (const float*)d_in[6];
  const float* b1 = (const float*)d_in[7];
  const float* w2 = (const float*)d_in[8];
  const float* b2 = (const float*)d_in[9];
  const float* w3 = (const float*)d_in[10];
  const float* b3 = (const float*)d_in[11];
  float* out = (float*)d_out;

  char* ws = (char*)d_ws;
  // region0: Xbf (bf16, written by gate, read by compact) aliases the front of
  // Outb (fp32, written by ffn_b AFTER compact in stream order) — disjoint lifetimes.
  float* Outb = (float*)ws;
  unsigned short* Xbf = (unsigned short*)ws;
  ws += (size_t)MAXROWS * C_DIM * 4;                       // 59.8 MB
  unsigned short* Xg = (unsigned short*)ws;  ws += (size_t)MAXROWS * C_DIM * 2;
  unsigned short* w1t = (unsigned short*)ws; ws += (size_t)E_NUM * C_DIM * HID * 2;
  unsigned short* w3t = (unsigned short*)ws; ws += (size_t)E_NUM * C_DIM * HID * 2;
  unsigned short* w2t = (unsigned short*)ws; ws += (size_t)E_NUM * HID * C_DIM * 2;
  unsigned short* H = (unsigned short*)ws;   ws += (size_t)MAXROWS * HID * 2;
  int* counts = (int*)ws;                    ws += 256;
  int* offsets = (int*)ws;                   ws += 256;
  int* tmap = (int*)ws;                      ws += 256;
  int* tok_list = (int*)ws;                  ws += (size_t)E_NUM * N_TOK * 4;
  int* pairE = (int*)ws;                     ws += (size_t)N_TOK * 2 * 4;
  int* pairPos = (int*)ws;                   ws += (size_t)N_TOK * 2 * 4;
  float* pairW = (float*)ws;                 ws += (size_t)N_TOK * 2 * 4;

  hipMemsetAsync(counts, 0, 64, stream);

  k_prep_w<<<dim3(HID / 32, C_DIM / 32, E_NUM), dim3(32, 8), 0, stream>>>(
      w1, w1t, C_DIM, HID, NKA, 6);
  k_prep_w<<<dim3(HID / 32, C_DIM / 32, E_NUM), dim3(32, 8), 0, stream>>>(
      w3, w3t, C_DIM, HID, NKA, 6);
  k_prep_w<<<dim3(C_DIM / 32, HID / 32, E_NUM), dim3(32, 8), 0, stream>>>(
      w2, w2t, HID, C_DIM, NKB, 7);
  k_gate<<<dim3(N_TOK / GT), dim3(256), 0, stream>>>(x, noise, wg, bg, wn, bn,
                                                     counts, tok_list, pairE, pairPos,
                                                     pairW, Xbf);
  k_scan<<<1, 32, 0, stream>>>(counts, offsets, tmap);
  k_compact<<<dim3(1024), dim3(256), 0, stream>>>(Xbf, offsets, counts, tok_list, Xg);
  k_ffn_a<<<dim3(768), dim3(256), 0, stream>>>(Xg, w1t, b1, w3t, b3, offsets, tmap, H);
  k_ffn_b<<<dim3(768), dim3(256), 0, stream>>>(H, w2t, b2, offsets, tmap, Outb);
  k_combine<<<dim3(HW / 32, C_DIM / 32, BATCH), dim3(32, 8), 0, stream>>>(
      Outb, offsets, counts, pairE, pairPos, pairW, out);
}